// Round 8
// baseline (839.618 us; speedup 1.0000x reference)
//
#include <hip/hip_runtime.h>
#include <cstdint>

#define NBOX 12288
#define NWORDS 192
#define POS_THRESH 0.15f
#define NMS_THRESH 0.7f

typedef unsigned long long u64;
typedef _Float16 half8 __attribute__((ext_vector_type(8)));
typedef float floatx4 __attribute__((ext_vector_type(4)));

// ---------------- Kernel 0a: zero the conv accumulator ----------------
__global__ __launch_bounds__(256) void zero_y(float4* __restrict__ Y) {
  Y[blockIdx.x * 256 + threadIdx.x] = float4{0.f, 0.f, 0.f, 0.f};
}

// ---------------- Kernel 0b: W (3,3,1024,512) -> WT[tap][n][c] fp16 h/l split ----------------
__global__ __launch_bounds__(256) void prep_wt(
    const float* __restrict__ Wc, _Float16* __restrict__ WTh, _Float16* __restrict__ WTl)
{
  __shared__ float tile[64][65];
  const int b = blockIdx.x;           // 9 taps * 16 c-tiles * 8 n-tiles = 1152
  const int tap = b >> 7;
  const int rem = b & 127;
  const int c0 = (rem >> 3) * 64, n0 = (rem & 7) * 64;
  const int t = threadIdx.x;
  #pragma unroll
  for (int i = 0; i < 16; ++i) {
    const int idx = i * 256 + t;
    const int c = idx >> 6, n = idx & 63;
    tile[n][c] = Wc[((size_t)(tap * 1024 + c0 + c)) * 512 + n0 + n];
  }
  __syncthreads();
  #pragma unroll
  for (int i = 0; i < 16; ++i) {
    const int idx = i * 256 + t;
    const int n = idx >> 6, c = idx & 63;
    const float v = tile[n][c];
    const _Float16 h = (_Float16)v;
    const _Float16 l = (_Float16)((v - (float)h) * 4096.0f);
    const size_t o = ((size_t)(tap * 512 + n0 + n)) * 1024 + c0 + c;
    WTh[o] = h;
    WTl[o] = l;
  }
}

// ---------------- Kernel 1: 3x3 conv via split-fp16 MFMA ----------------
#define AROW 40
#define AS_PLANE (4 * 66 * AROW)
#define BS_PLANE (128 * AROW)
__global__ __launch_bounds__(256, 1) void conv_mfma(
    const float* __restrict__ X, const _Float16* __restrict__ WTh,
    const _Float16* __restrict__ WTl, float* __restrict__ Y)
{
  __shared__ _Float16 As[2 * AS_PLANE];   // 42,240 B
  __shared__ _Float16 Bs[2 * BS_PLANE];   // 20,480 B
  const int bid = blockIdx.x;
  const int ks = bid & 1;
  const int nt = (bid >> 1) & 3;
  const int mt = bid >> 3;
  const int t = threadIdx.x;
  const int lane = t & 63, wid = t >> 6;
  const int wm = wid >> 1, wn = wid & 1;
  const int lrow = lane & 15, quad = lane >> 4;

  floatx4 accH[4][4], accL[4][4];
  #pragma unroll
  for (int i = 0; i < 4; ++i)
    #pragma unroll
    for (int j = 0; j < 4; ++j) { accH[i][j] = (floatx4)0.f; accL[i][j] = (floatx4)0.f; }

  for (int kc = 0; kc < 16; ++kc) {
    const int c0 = ks * 512 + kc * 32;
    __syncthreads();
    for (int r = t; r < 264; r += 256) {
      const int yy = r / 66;
      const int xx = r - yy * 66;
      const int yi = mt * 2 + yy - 1;
      const int xi = xx - 1;
      _Float16* dsth = &As[(yy * 66 + xx) * AROW];
      _Float16* dstl = dsth + AS_PLANE;
      if (yi >= 0 && yi < 64 && xi >= 0 && xi < 64) {
        const float4* src = (const float4*)(X + ((size_t)(yi * 64 + xi)) * 1024 + c0);
        #pragma unroll
        for (int j = 0; j < 4; ++j) {
          const float4 va = src[2 * j], vb = src[2 * j + 1];
          const float f[8] = {va.x, va.y, va.z, va.w, vb.x, vb.y, vb.z, vb.w};
          half8 hh, hl;
          #pragma unroll
          for (int e = 0; e < 8; ++e) {
            const _Float16 h = (_Float16)f[e];
            hh[e] = h;
            hl[e] = (_Float16)((f[e] - (float)h) * 4096.0f);
          }
          *(half8*)&dsth[j * 8] = hh;
          *(half8*)&dstl[j * 8] = hl;
        }
      } else {
        const half8 z = (half8)(_Float16)0.f;
        #pragma unroll
        for (int j = 0; j < 4; ++j) { *(half8*)&dsth[j * 8] = z; *(half8*)&dstl[j * 8] = z; }
      }
    }
    for (int tap = 0; tap < 9; ++tap) {
      if (tap > 0) __syncthreads();
      {
        const int hl = t >> 7, n = t & 127;
        const _Float16* src = (hl ? WTl : WTh) +
            ((size_t)(tap * 512 + nt * 128 + n)) * 1024 + c0;
        _Float16* dst = &Bs[hl * BS_PLANE + n * AROW];
        #pragma unroll
        for (int j = 0; j < 4; ++j)
          *(half8*)&dst[j * 8] = *(const half8*)&src[j * 8];
      }
      __syncthreads();
      const int dy = tap / 3 - 1, dx = tap - (tap / 3) * 3 - 1;
      const int yy = wm + dy + 1;
      const int xxb = dx + 1;
      half8 Ah[4], Al[4], Bh[4], Bl[4];
      #pragma unroll
      for (int fm = 0; fm < 4; ++fm) {
        const int idx = (yy * 66 + xxb + fm * 16 + lrow) * AROW + quad * 8;
        Ah[fm] = *(const half8*)&As[idx];
        Al[fm] = *(const half8*)&As[idx + AS_PLANE];
      }
      #pragma unroll
      for (int fn = 0; fn < 4; ++fn) {
        const int idx = (wn * 64 + fn * 16 + lrow) * AROW + quad * 8;
        Bh[fn] = *(const half8*)&Bs[idx];
        Bl[fn] = *(const half8*)&Bs[idx + BS_PLANE];
      }
      #pragma unroll
      for (int fm = 0; fm < 4; ++fm)
        #pragma unroll
        for (int fn = 0; fn < 4; ++fn) {
          accH[fm][fn] = __builtin_amdgcn_mfma_f32_16x16x32_f16(Ah[fm], Bh[fn], accH[fm][fn], 0, 0, 0);
          accL[fm][fn] = __builtin_amdgcn_mfma_f32_16x16x32_f16(Al[fm], Bh[fn], accL[fm][fn], 0, 0, 0);
          accL[fm][fn] = __builtin_amdgcn_mfma_f32_16x16x32_f16(Ah[fm], Bl[fn], accL[fm][fn], 0, 0, 0);
        }
    }
  }
  const int m0 = mt * 128 + wm * 64;
  const int n0 = nt * 128 + wn * 64;
  #pragma unroll
  for (int fm = 0; fm < 4; ++fm)
    #pragma unroll
    for (int fn = 0; fn < 4; ++fn) {
      const int n = n0 + fn * 16 + lrow;
      #pragma unroll
      for (int r = 0; r < 4; ++r) {
        const int m = m0 + fm * 16 + quad * 4 + r;
        atomicAdd(&Y[(size_t)m * 512 + n],
                  accH[fm][fn][r] + accL[fm][fn][r] * (1.0f / 4096.0f));
      }
    }
}

// ---------------- Kernel 2: bias+ReLU + 1x1 heads + softmax(6) + decode + ext init ----------------
__global__ __launch_bounds__(64) void heads_decode(
    const float* __restrict__ Yx, const float* __restrict__ Bc,
    const float* __restrict__ Wcls, const float* __restrict__ bcls,
    const float* __restrict__ Wreg, const float* __restrict__ breg,
    float* __restrict__ boxes, float* __restrict__ scores, int* __restrict__ ext)
{
  __shared__ float xs[512];
  const int pos = blockIdx.x;
  const int l = threadIdx.x;
  if (l == 0 && pos < NWORDS) ext[pos] = pos;
  const float* xrow = Yx + (size_t)pos * 512;
  float4 v0 = *(const float4*)&xrow[l * 8];
  float4 v1 = *(const float4*)&xrow[l * 8 + 4];
  const float4 b0 = *(const float4*)&Bc[l * 8];
  const float4 b1 = *(const float4*)&Bc[l * 8 + 4];
  xs[l * 8 + 0] = fmaxf(v0.x + b0.x, 0.f);
  xs[l * 8 + 1] = fmaxf(v0.y + b0.y, 0.f);
  xs[l * 8 + 2] = fmaxf(v0.z + b0.z, 0.f);
  xs[l * 8 + 3] = fmaxf(v0.w + b0.w, 0.f);
  xs[l * 8 + 4] = fmaxf(v1.x + b1.x, 0.f);
  xs[l * 8 + 5] = fmaxf(v1.y + b1.y, 0.f);
  xs[l * 8 + 6] = fmaxf(v1.z + b1.z, 0.f);
  xs[l * 8 + 7] = fmaxf(v1.w + b1.w, 0.f);
  __syncthreads();

  const float* wp;
  int oc;
  float bini;
  if (l < 6)       { wp = Wcls + l;       oc = 6;  bini = bcls[l]; }
  else if (l < 18) { wp = Wreg + (l - 6); oc = 12; bini = breg[l - 6]; }
  else             { wp = Wcls;           oc = 0;  bini = 0.f; }
  float acc = bini;
  const float* p = wp;
  #pragma unroll 4
  for (int c = 0; c < 512; ++c) { acc = fmaf(xs[c], *p, acc); p += oc; }

  const float l0 = __shfl(acc, 0), l1 = __shfl(acc, 1), l2 = __shfl(acc, 2);
  const float l3 = __shfl(acc, 3), l4 = __shfl(acc, 4), l5 = __shfl(acc, 5);
  const int a = (l < 3) ? l : 0;
  const float d0 = __shfl(acc, 6 + a * 4 + 0);
  const float d1 = __shfl(acc, 6 + a * 4 + 1);
  const float d2 = __shfl(acc, 6 + a * 4 + 2);
  const float d3 = __shfl(acc, 6 + a * 4 + 3);

  const float mx = fmaxf(fmaxf(fmaxf(l0, l1), fmaxf(l2, l3)), fmaxf(l4, l5));
  const float e0 = expf(l0 - mx), e1 = expf(l1 - mx), e2 = expf(l2 - mx);
  const float e3 = expf(l3 - mx), e4 = expf(l4 - mx), e5 = expf(l5 - mx);
  const float den = ((((e0 + e1) + e2) + e3) + e4) + e5;
  const float esel = (a == 0) ? e1 : ((a == 1) ? e3 : e5);
  const float sc = esel / den;

  const int px = pos & 63, py = pos >> 6;
  const float cx = (px + 0.5f) * 16.0f;
  const float cy = (py + 0.5f) * 16.0f;
  const float ratio = (a == 0) ? 0.5f : ((a == 1) ? 1.0f : 2.0f);
  const float sq = sqrtf(ratio);
  const float wsz = 128.0f * sq;
  const float hsz = 128.0f / sq;
  const float a0 = cx - wsz * 0.5f;
  const float a1 = cy - hsz * 0.5f;
  const float a2 = cx + wsz * 0.5f;
  const float a3 = cy + hsz * 0.5f;
  const float w = a2 - a0, h = a3 - a1;
  const float xc = __fadd_rn(__fmul_rn(__fadd_rn(a0, a2), 0.5f), __fmul_rn(d0, w));
  const float yc = __fadd_rn(__fmul_rn(__fadd_rn(a1, a3), 0.5f), __fmul_rn(d1, h));
  const float nw = __fmul_rn(w, expf(d2));
  const float nh = __fmul_rn(h, expf(d3));
  float4 box;
  box.x = __fsub_rn(xc, __fmul_rn(nw, 0.5f));
  box.y = __fsub_rn(yc, __fmul_rn(nh, 0.5f));
  box.z = __fadd_rn(xc, __fmul_rn(nw, 0.5f));
  box.w = __fadd_rn(yc, __fmul_rn(nh, 0.5f));

  if (l < 3) {
    const int idx = pos * 3 + a;
    *(float4*)&boxes[idx * 4] = box;
    scores[idx] = sc;
  }
}

// ---------------- Kernel 3: suppression bit-matrix (column-major) + extent ----------------
__global__ __launch_bounds__(256) void build_mask(
    const float* __restrict__ boxes, u64* __restrict__ maskT,
    int* __restrict__ ext)
{
  const int w  = blockIdx.x;
  const int ci = blockIdx.y;
  if (w < ci) return;
  __shared__ float4 rb[64];
  __shared__ int anyf;
  const int t = threadIdx.x;
  const int lane = t & 63, wid = t >> 6;
  if (t == 0) anyf = 0;
  if (t < 64) rb[t] = *(const float4*)&boxes[(ci * 64 + t) * 4];
  const float4 cb = *(const float4*)&boxes[(w * 64 + lane) * 4];
  const float careaa = __fmul_rn(cb.z - cb.x, cb.w - cb.y);
  const int jglob = w * 64 + lane;
  __syncthreads();
  bool any = false;
  for (int rr = 0; rr < 16; ++rr) {
    const int r = wid * 16 + rr;
    const int row = ci * 64 + r;
    const float4 rx = rb[r];
    const float ra = __fmul_rn(rx.z - rx.x, rx.w - rx.y);
    const float xx1 = fmaxf(rx.x, cb.x);
    const float yy1 = fmaxf(rx.y, cb.y);
    const float xx2 = fminf(rx.z, cb.z);
    const float yy2 = fminf(rx.w, cb.w);
    const float iw = fmaxf(__fsub_rn(xx2, xx1), 0.f);
    const float ih = fmaxf(__fsub_rn(yy2, yy1), 0.f);
    const float inter = __fmul_rn(iw, ih);
    const float den = __fadd_rn(__fsub_rn(__fadd_rn(ra, careaa), inter), 1e-9f);
    const float iou = __fdiv_rn(inter, den);
    const bool bit = (iou > NMS_THRESH) && (jglob > row);
    any |= bit;
    const u64 word = __ballot(bit ? 1 : 0);
    if (lane == 0) maskT[(size_t)w * NBOX + row] = word;
  }
  if (any) anyf = 1;
  __syncthreads();
  if (t == 0 && anyf && w > ci) atomicMax(&ext[ci], w);
}

// ---------------- Kernel 4: greedy NMS scan, v9b: 4-word chunks (48 steps) ----------------
// Empirical law from v3-v8: ~1.6-2.1us per word-step regardless of structure. So
// amortize: 4 words (256 boxes) per step, 48 steps. Geometry bounds suppression
// reach (IoU>0.7 => drow<=1, dx<=2, ~3.2 words), so cross-chunk suppression lands
// in columns c4+4..c4+11 (2.5x margin; ext-guarded overflow loop beyond). Skeleton
// = v4 (best measured): 4 waves, per-wave-replicated scalar greedy chain, LDS
// alive + atomicAnd, one raw barrier per step; ping-pong A/B register prefetch.
// In-chunk cross-word suppression accumulated scalarly inside the accept rounds.
__device__ __forceinline__ u64 rl64v(u64 v, int ln) {
  const unsigned a = (unsigned)__builtin_amdgcn_readlane((int)(unsigned)v, ln);
  const unsigned b = (unsigned)__builtin_amdgcn_readlane((int)(unsigned)(v >> 32), ln);
  return ((u64)b << 32) | (u64)a;
}
__device__ __forceinline__ u64 rfl64(u64 v) {
  const unsigned lo = (unsigned)__builtin_amdgcn_readfirstlane((int)(unsigned)v);
  const unsigned hi = (unsigned)__builtin_amdgcn_readfirstlane((int)(unsigned)(v >> 32));
  return ((u64)hi << 32) | (u64)lo;
}
__device__ __forceinline__ u64 shflxor64(u64 v, int m) {
  const int lo = __shfl_xor((int)(unsigned)v, m);
  const int hi = __shfl_xor((int)(unsigned)(v >> 32), m);
  return ((u64)(unsigned)hi << 32) | (unsigned)lo;
}
__device__ __forceinline__ u64 build_alive(const float* sp) {
  u64 w = 0ull;
  const float4* p = (const float4*)sp;
  #pragma unroll
  for (int q = 0; q < 16; ++q) {
    const float4 s = p[q];
    if (s.x > POS_THRESH) w |= (1ull << (q * 4 + 0));
    if (s.y > POS_THRESH) w |= (1ull << (q * 4 + 1));
    if (s.z > POS_THRESH) w |= (1ull << (q * 4 + 2));
    if (s.w > POS_THRESH) w |= (1ull << (q * 4 + 3));
  }
  return w;
}

// XACC: inside a greedy round, accumulate cross-word suppression of accepted bits.
// Uses round locals b0_..b3_, k1_..k3_ (in scope where expanded).
#define XACC(XR_, SV_)                                                          \
  {                                                                             \
    const u64 xa_ = rl64v(XR_, b0_);                                            \
    const u64 xb_ = rl64v(XR_, b1_ & 63);                                       \
    const u64 xc_ = rl64v(XR_, b2_ & 63);                                       \
    const u64 xd_ = rl64v(XR_, b3_ & 63);                                       \
    SV_ |= xa_ | (xb_ & k1_) | (xc_ & k2_) | (xd_ & k3_);                       \
  }

// scalar greedy over one 64-bit word (4-wide speculative rounds, exact greedy);
// XSTMTS_ expands inside each round after k3_ is computed.
#define PA_WORD_X(DG_, AWI_, AWF_, XSTMTS_)                                     \
  {                                                                             \
    const u64 awv_ = (AWI_);                                                    \
    u64 supp_ = 0ull;                                                           \
    u64 pend_ = awv_;                                                           \
    while (pend_) {                                                             \
      const u64 p0_ = pend_;                                                    \
      const u64 p1_ = p0_ & (p0_ - 1);                                          \
      const u64 p2_ = p1_ & (p1_ - 1);                                          \
      const u64 p3_ = p2_ & (p2_ - 1);                                          \
      const int b0_ = __builtin_ctzll(p0_);                                     \
      const int b1_ = p1_ ? __builtin_ctzll(p1_) : 64;                          \
      const int b2_ = p2_ ? __builtin_ctzll(p2_) : 64;                          \
      const int b3_ = p3_ ? __builtin_ctzll(p3_) : 64;                          \
      const u64 r0_ = rl64v(DG_, b0_);                                          \
      const u64 r1_ = rl64v(DG_, b1_ & 63);                                     \
      const u64 r2_ = rl64v(DG_, b2_ & 63);                                     \
      const u64 r3_ = rl64v(DG_, b3_ & 63);                                     \
      u64 sp_ = supp_ | r0_;                                                    \
      u64 done_ = 1ull << b0_;                                                  \
      const u64 k1_ = ((b1_ < 64) && !((sp_ >> (b1_ & 63)) & 1ull)) ? ~0ull : 0ull; \
      sp_ |= r1_ & k1_; done_ |= (1ull << (b1_ & 63)) & k1_;                    \
      const u64 k2_ = ((b2_ < 64) && !((sp_ >> (b2_ & 63)) & 1ull)) ? ~0ull : 0ull; \
      sp_ |= r2_ & k2_; done_ |= (1ull << (b2_ & 63)) & k2_;                    \
      const u64 k3_ = ((b3_ < 64) && !((sp_ >> (b3_ & 63)) & 1ull)) ? ~0ull : 0ull; \
      sp_ |= r3_ & k3_; done_ |= (1ull << (b3_ & 63)) & k3_;                    \
      XSTMTS_                                                                   \
      supp_ = sp_;                                                              \
      pend_ &= ~(sp_ | done_);                                                  \
    }                                                                           \
    AWF_ = awv_ & ~supp_;                                                       \
  }

#define PA_W0(DG_, XA_, XB_, XC_, AWI_, AWF_, SA_, SB_, SC_)                    \
  PA_WORD_X(DG_, AWI_, AWF_, XACC(XA_, SA_) XACC(XB_, SB_) XACC(XC_, SC_))
#define PA_W1(DG_, XA_, XB_, AWI_, AWF_, SA_, SB_)                              \
  PA_WORD_X(DG_, AWI_, AWF_, XACC(XA_, SA_) XACC(XB_, SB_))
#define PA_W2(DG_, XA_, AWI_, AWF_, SA_)                                        \
  PA_WORD_X(DG_, AWI_, AWF_, XACC(XA_, SA_))
#define PA_W3(DG_, AWI_, AWF_)                                                  \
  PA_WORD_X(DG_, AWI_, AWF_, )

// branchless clamped prefetch of chunk C4_ into register set S (ping-pong A/B)
#define NMS_PFC(C4_, S)                                                         \
  do {                                                                          \
    const int cb_ = ((C4_) <= NWORDS - 4) ? (C4_) : (NWORDS - 4);               \
    DG0##S = maskT[(size_t)(cb_ + 0) * NBOX + (size_t)(cb_ + 0) * 64 + lane];   \
    DG1##S = maskT[(size_t)(cb_ + 1) * NBOX + (size_t)(cb_ + 1) * 64 + lane];   \
    DG2##S = maskT[(size_t)(cb_ + 2) * NBOX + (size_t)(cb_ + 2) * 64 + lane];   \
    DG3##S = maskT[(size_t)(cb_ + 3) * NBOX + (size_t)(cb_ + 3) * 64 + lane];   \
    X01##S = maskT[(size_t)(cb_ + 1) * NBOX + (size_t)(cb_ + 0) * 64 + lane];   \
    X02##S = maskT[(size_t)(cb_ + 2) * NBOX + (size_t)(cb_ + 0) * 64 + lane];   \
    X03##S = maskT[(size_t)(cb_ + 3) * NBOX + (size_t)(cb_ + 0) * 64 + lane];   \
    X12##S = maskT[(size_t)(cb_ + 2) * NBOX + (size_t)(cb_ + 1) * 64 + lane];   \
    X13##S = maskT[(size_t)(cb_ + 3) * NBOX + (size_t)(cb_ + 1) * 64 + lane];   \
    X23##S = maskT[(size_t)(cb_ + 3) * NBOX + (size_t)(cb_ + 2) * 64 + lane];   \
    {                                                                           \
      int tq_ = cb_ + 4 + col;                                                  \
      tq_ = (tq_ < NWORDS) ? tq_ : (NWORDS - 1);                                \
      const u64* mp_ = maskT + (size_t)tq_ * NBOX + (size_t)(cb_ + msw) * 64 + moct * 8; \
      M##S##0 = mp_[0]; M##S##1 = mp_[1]; M##S##2 = mp_[2]; M##S##3 = mp_[3];   \
      M##S##4 = mp_[4]; M##S##5 = mp_[5]; M##S##6 = mp_[6]; M##S##7 = mp_[7];   \
    }                                                                           \
  } while (0)

#define NMS_STEP(C4_, S, P)                                                     \
  do {                                                                          \
    NMS_PFC((C4_) + 4, P);                                                      \
    const u64 v0_ = alive[(C4_) + 0];                                           \
    const u64 v1_ = alive[(C4_) + 1];                                           \
    const u64 v2_ = alive[(C4_) + 2];                                           \
    const u64 v3_ = alive[(C4_) + 3];                                           \
    const u64 aw0i_ = rfl64(v0_);                                               \
    const u64 aw1r_ = rfl64(v1_);                                               \
    const u64 aw2r_ = rfl64(v2_);                                               \
    const u64 aw3r_ = rfl64(v3_);                                               \
    const int exw_ = ((C4_) < 64) ? ex0 : (((C4_) < 128) ? ex1 : ex2);          \
    int e4_ = __builtin_amdgcn_readlane(exw_, (C4_) & 63);                      \
    { int ee_;                                                                  \
      ee_ = __builtin_amdgcn_readlane(exw_, ((C4_) + 1) & 63); if (ee_ > e4_) e4_ = ee_; \
      ee_ = __builtin_amdgcn_readlane(exw_, ((C4_) + 2) & 63); if (ee_ > e4_) e4_ = ee_; \
      ee_ = __builtin_amdgcn_readlane(exw_, ((C4_) + 3) & 63); if (ee_ > e4_) e4_ = ee_; } \
    u64 s1_ = 0ull, s2_ = 0ull, s3_ = 0ull;                                     \
    u64 aw0f_, aw1f_, aw2f_, aw3f_;                                             \
    PA_W0(DG0##S, X01##S, X02##S, X03##S, aw0i_, aw0f_, s1_, s2_, s3_)          \
    PA_W1(DG1##S, X12##S, X13##S, aw1r_ & ~s1_, aw1f_, s2_, s3_)                \
    PA_W2(DG2##S, X23##S, aw2r_ & ~s2_, aw2f_, s3_)                             \
    PA_W3(DG3##S, aw3r_ & ~s3_, aw3f_)                                          \
    const u64 myaw_ = (msw == 0) ? aw0f_ : ((msw == 1) ? aw1f_ : ((msw == 2) ? aw2f_ : aw3f_)); \
    const unsigned selb_ = (unsigned)((myaw_ >> (moct * 8)) & 0xffull);         \
    u64 part_ = 0ull;                                                           \
    if (selb_ & 1u)   part_ |= M##S##0;                                         \
    if (selb_ & 2u)   part_ |= M##S##1;                                         \
    if (selb_ & 4u)   part_ |= M##S##2;                                         \
    if (selb_ & 8u)   part_ |= M##S##3;                                         \
    if (selb_ & 16u)  part_ |= M##S##4;                                         \
    if (selb_ & 32u)  part_ |= M##S##5;                                         \
    if (selb_ & 64u)  part_ |= M##S##6;                                         \
    if (selb_ & 128u) part_ |= M##S##7;                                         \
    part_ |= shflxor64(part_, 1);                                               \
    part_ |= shflxor64(part_, 2);                                               \
    part_ |= shflxor64(part_, 4);                                               \
    part_ |= shflxor64(part_, 8);                                               \
    part_ |= shflxor64(part_, 16);                                              \
    const int tcol_ = (C4_) + 4 + col;                                          \
    if (oo == 0 && tcol_ < NWORDS && part_)                                     \
      atomicAnd((unsigned long long*)&alive[tcol_], ~part_);                    \
    if (t == 0) {                                                               \
      alive[(C4_) + 0] = aw0f_;                                                 \
      alive[(C4_) + 1] = aw1f_;                                                 \
      alive[(C4_) + 2] = aw2f_;                                                 \
      alive[(C4_) + 3] = aw3f_;                                                 \
    }                                                                           \
    if (e4_ >= (C4_) + 12) { /* rare overflow beyond the 8-col window */        \
      for (int bb_ = (C4_) + 12; bb_ <= e4_; bb_ += 8) {                        \
        const int tc2_ = bb_ + col;                                             \
        u64 pt_ = 0ull;                                                         \
        if (tc2_ <= e4_) {                                                      \
          const u64* pov_ = maskT + (size_t)tc2_ * NBOX + (size_t)((C4_) + msw) * 64 + moct * 8; \
          if (selb_ & 1u)   pt_ |= pov_[0];                                     \
          if (selb_ & 2u)   pt_ |= pov_[1];                                     \
          if (selb_ & 4u)   pt_ |= pov_[2];                                     \
          if (selb_ & 8u)   pt_ |= pov_[3];                                     \
          if (selb_ & 16u)  pt_ |= pov_[4];                                     \
          if (selb_ & 32u)  pt_ |= pov_[5];                                     \
          if (selb_ & 64u)  pt_ |= pov_[6];                                     \
          if (selb_ & 128u) pt_ |= pov_[7];                                     \
        }                                                                       \
        pt_ |= shflxor64(pt_, 1);                                               \
        pt_ |= shflxor64(pt_, 2);                                               \
        pt_ |= shflxor64(pt_, 4);                                               \
        pt_ |= shflxor64(pt_, 8);                                               \
        pt_ |= shflxor64(pt_, 16);                                              \
        if (oo == 0 && tc2_ <= e4_ && pt_)                                      \
          atomicAnd((unsigned long long*)&alive[tc2_], ~pt_);                   \
      }                                                                         \
    }                                                                           \
    asm volatile("s_waitcnt lgkmcnt(0)" ::: "memory");                          \
    __builtin_amdgcn_s_barrier();                                               \
    asm volatile("" ::: "memory");                                              \
  } while (0)

__global__ __launch_bounds__(256) void nms_scan(
    const float* __restrict__ scores, const u64* __restrict__ maskT,
    const int* __restrict__ ext, u64* __restrict__ aliveOut)
{
  __shared__ u64 alive[NWORDS];
  const int t = threadIdx.x;
  const int lane = t & 63;
  const int col = t >> 5;          // 0..7: downstream column (word c4+4+col)
  const int oo = t & 31;           // (src word, octet) pair index
  const int msw = oo >> 3;         // 0..3: source word within chunk
  const int moct = oo & 7;         // 0..7: row octet within source word

  if (t < NWORDS) alive[t] = build_alive(scores + (size_t)t * 64);
  const int ex0 = ext[lane];       // replicated per wave for readlane access
  const int ex1 = ext[64 + lane];
  const int ex2 = ext[128 + lane];

  u64 DG0A, DG1A, DG2A, DG3A, X01A, X02A, X03A, X12A, X13A, X23A;
  u64 MA0, MA1, MA2, MA3, MA4, MA5, MA6, MA7;
  u64 DG0B, DG1B, DG2B, DG3B, X01B, X02B, X03B, X12B, X13B, X23B;
  u64 MB0, MB1, MB2, MB3, MB4, MB5, MB6, MB7;

  NMS_PFC(0, A);
  __syncthreads();

  for (int c4 = 0; c4 < NWORDS; c4 += 8) {
    NMS_STEP(c4, A, B);
    NMS_STEP(c4 + 4, B, A);
  }
  if (t < NWORDS) aliveOut[t] = alive[t];
}

// ---------------- Kernel 5: masked output ----------------
__global__ __launch_bounds__(256) void write_output(
    const float* __restrict__ boxes, const u64* __restrict__ alive,
    float* __restrict__ out)
{
  const int i = blockIdx.x * 256 + threadIdx.x;
  if (i < NBOX) {
    const bool k = (alive[i >> 6] >> (i & 63)) & 1ull;
    const float4 b = *(const float4*)&boxes[i * 4];
    const float4 z = {0.f, 0.f, 0.f, 0.f};
    *(float4*)&out[i * 4] = k ? b : z;
  }
}

extern "C" void kernel_launch(void* const* d_in, const int* in_sizes, int n_in,
                              void* d_out, int out_size, void* d_ws, size_t ws_size,
                              hipStream_t stream) {
  const float* X    = (const float*)d_in[0];  // (1,64,64,1024)
  const float* Wc   = (const float*)d_in[1];  // (3,3,1024,512)
  const float* Bc   = (const float*)d_in[2];  // (512,)
  const float* Wcls = (const float*)d_in[3];  // (1,1,512,6)
  const float* bcls = (const float*)d_in[4];  // (6,)
  const float* Wreg = (const float*)d_in[5];  // (1,1,512,12)
  const float* breg = (const float*)d_in[6];  // (12,)

  char* ws = (char*)d_ws;
  float*     Y      = (float*)    (ws);                 // 8,388,608 B (raw conv sums)
  float*     boxes  = (float*)    (ws + 8388608);       //   196,608 B
  float*     scores = (float*)    (ws + 8585216);       //    49,152 B
  u64*       aliveG = (u64*)      (ws + 8634368);       //     1,536 B
  int*       extG   = (int*)      (ws + 8635904);       //       768 B
  // conv phase uses [8,636,672 .. 27,511,040) for WTh+WTl; maskT reuses the
  // SAME region after conv is done (both exactly 18,874,368 B).
  _Float16*  WTh    = (_Float16*) (ws + 8636672);       // 9,437,184 B
  _Float16*  WTl    = (_Float16*) (ws + 18073856);      // 9,437,184 B
  u64*       maskT  = (u64*)      (ws + 8636672);       // 18,874,368 B (post-conv)

  zero_y      <<<2048, 256, 0, stream>>>((float4*)Y);
  prep_wt     <<<1152, 256, 0, stream>>>(Wc, WTh, WTl);
  conv_mfma   <<<256, 256, 0, stream>>>(X, WTh, WTl, Y);
  heads_decode<<<4096, 64, 0, stream>>>(Y, Bc, Wcls, bcls, Wreg, breg, boxes, scores, extG);
  build_mask  <<<dim3(192, 192), 256, 0, stream>>>(boxes, maskT, extG);
  nms_scan    <<<1, 256, 0, stream>>>(scores, maskT, extG, aliveG);
  write_output<<<48, 256, 0, stream>>>(boxes, aliveG, (float*)d_out);
}

// Round 9
// 611.965 us; speedup vs baseline: 1.3720x; 1.3720x over previous
//
#include <hip/hip_runtime.h>
#include <cstdint>

#define NBOX 12288
#define NWORDS 192
#define POS_THRESH 0.15f
#define NMS_THRESH 0.7f

typedef unsigned long long u64;
typedef _Float16 half8 __attribute__((ext_vector_type(8)));
typedef float floatx4 __attribute__((ext_vector_type(4)));

// ---------------- Kernel 0a: zero the conv accumulator ----------------
__global__ __launch_bounds__(256) void zero_y(float4* __restrict__ Y) {
  Y[blockIdx.x * 256 + threadIdx.x] = float4{0.f, 0.f, 0.f, 0.f};
}

// ---------------- Kernel 0b: W (3,3,1024,512) -> WT[tap][n][c] fp16 h/l split ----------------
// l pre-scaled by 4096 so it stays in fp16 normal range (w~0.01 -> wl~2e-6 would be denormal).
__global__ __launch_bounds__(256) void prep_wt(
    const float* __restrict__ Wc, _Float16* __restrict__ WTh, _Float16* __restrict__ WTl)
{
  __shared__ float tile[64][65];
  const int b = blockIdx.x;           // 9 taps * 16 c-tiles * 8 n-tiles = 1152
  const int tap = b >> 7;
  const int rem = b & 127;
  const int c0 = (rem >> 3) * 64, n0 = (rem & 7) * 64;
  const int t = threadIdx.x;
  #pragma unroll
  for (int i = 0; i < 16; ++i) {
    const int idx = i * 256 + t;
    const int c = idx >> 6, n = idx & 63;
    tile[n][c] = Wc[((size_t)(tap * 1024 + c0 + c)) * 512 + n0 + n];
  }
  __syncthreads();
  #pragma unroll
  for (int i = 0; i < 16; ++i) {
    const int idx = i * 256 + t;
    const int n = idx >> 6, c = idx & 63;
    const float v = tile[n][c];
    const _Float16 h = (_Float16)v;
    const _Float16 l = (_Float16)((v - (float)h) * 4096.0f);
    const size_t o = ((size_t)(tap * 512 + n0 + n)) * 1024 + c0 + c;
    WTh[o] = h;
    WTl[o] = l;
  }
}

// ---------------- Kernel 1: 3x3 conv via split-fp16 MFMA ----------------
#define AROW 40                 // 32 k-halves padded to 40 (80B = 20 banks: 2-way only)
#define AS_PLANE (4 * 66 * AROW)
#define BS_PLANE (128 * AROW)
__global__ __launch_bounds__(256, 1) void conv_mfma(
    const float* __restrict__ X, const _Float16* __restrict__ WTh,
    const _Float16* __restrict__ WTl, float* __restrict__ Y)
{
  __shared__ _Float16 As[2 * AS_PLANE];   // 42,240 B
  __shared__ _Float16 Bs[2 * BS_PLANE];   // 20,480 B
  const int bid = blockIdx.x;
  const int ks = bid & 1;
  const int nt = (bid >> 1) & 3;
  const int mt = bid >> 3;
  const int t = threadIdx.x;
  const int lane = t & 63, wid = t >> 6;
  const int wm = wid >> 1, wn = wid & 1;
  const int lrow = lane & 15, quad = lane >> 4;

  floatx4 accH[4][4], accL[4][4];
  #pragma unroll
  for (int i = 0; i < 4; ++i)
    #pragma unroll
    for (int j = 0; j < 4; ++j) { accH[i][j] = (floatx4)0.f; accL[i][j] = (floatx4)0.f; }

  for (int kc = 0; kc < 16; ++kc) {
    const int c0 = ks * 512 + kc * 32;
    __syncthreads();   // prior chunk readers done
    // ---- stage A halo: 264 (yy,xx) rows x 32 ch, split to h/l ----
    for (int r = t; r < 264; r += 256) {
      const int yy = r / 66;
      const int xx = r - yy * 66;
      const int yi = mt * 2 + yy - 1;
      const int xi = xx - 1;
      _Float16* dsth = &As[(yy * 66 + xx) * AROW];
      _Float16* dstl = dsth + AS_PLANE;
      if (yi >= 0 && yi < 64 && xi >= 0 && xi < 64) {
        const float4* src = (const float4*)(X + ((size_t)(yi * 64 + xi)) * 1024 + c0);
        #pragma unroll
        for (int j = 0; j < 4; ++j) {
          const float4 va = src[2 * j], vb = src[2 * j + 1];
          const float f[8] = {va.x, va.y, va.z, va.w, vb.x, vb.y, vb.z, vb.w};
          half8 hh, hl;
          #pragma unroll
          for (int e = 0; e < 8; ++e) {
            const _Float16 h = (_Float16)f[e];
            hh[e] = h;
            hl[e] = (_Float16)((f[e] - (float)h) * 4096.0f);
          }
          *(half8*)&dsth[j * 8] = hh;
          *(half8*)&dstl[j * 8] = hl;
        }
      } else {
        const half8 z = (half8)(_Float16)0.f;
        #pragma unroll
        for (int j = 0; j < 4; ++j) { *(half8*)&dsth[j * 8] = z; *(half8*)&dstl[j * 8] = z; }
      }
    }
    for (int tap = 0; tap < 9; ++tap) {
      if (tap > 0) __syncthreads();   // prior tap's B readers done
      {   // ---- stage B: 256 rows (hl,n) x 32 halves ----
        const int hl = t >> 7, n = t & 127;
        const _Float16* src = (hl ? WTl : WTh) +
            ((size_t)(tap * 512 + nt * 128 + n)) * 1024 + c0;
        _Float16* dst = &Bs[hl * BS_PLANE + n * AROW];
        #pragma unroll
        for (int j = 0; j < 4; ++j)
          *(half8*)&dst[j * 8] = *(const half8*)&src[j * 8];
      }
      __syncthreads();   // A (first tap) + B visible
      const int dy = tap / 3 - 1, dx = tap - (tap / 3) * 3 - 1;
      const int yy = wm + dy + 1;
      const int xxb = dx + 1;
      half8 Ah[4], Al[4], Bh[4], Bl[4];
      #pragma unroll
      for (int fm = 0; fm < 4; ++fm) {
        const int idx = (yy * 66 + xxb + fm * 16 + lrow) * AROW + quad * 8;
        Ah[fm] = *(const half8*)&As[idx];
        Al[fm] = *(const half8*)&As[idx + AS_PLANE];
      }
      #pragma unroll
      for (int fn = 0; fn < 4; ++fn) {
        const int idx = (wn * 64 + fn * 16 + lrow) * AROW + quad * 8;
        Bh[fn] = *(const half8*)&Bs[idx];
        Bl[fn] = *(const half8*)&Bs[idx + BS_PLANE];
      }
      #pragma unroll
      for (int fm = 0; fm < 4; ++fm)
        #pragma unroll
        for (int fn = 0; fn < 4; ++fn) {
          accH[fm][fn] = __builtin_amdgcn_mfma_f32_16x16x32_f16(Ah[fm], Bh[fn], accH[fm][fn], 0, 0, 0);
          accL[fm][fn] = __builtin_amdgcn_mfma_f32_16x16x32_f16(Al[fm], Bh[fn], accL[fm][fn], 0, 0, 0);
          accL[fm][fn] = __builtin_amdgcn_mfma_f32_16x16x32_f16(Ah[fm], Bl[fn], accL[fm][fn], 0, 0, 0);
        }
    }
  }
  // ---- epilogue: combine scales, atomic-accumulate (2 K-slices per output) ----
  const int m0 = mt * 128 + wm * 64;
  const int n0 = nt * 128 + wn * 64;
  #pragma unroll
  for (int fm = 0; fm < 4; ++fm)
    #pragma unroll
    for (int fn = 0; fn < 4; ++fn) {
      const int n = n0 + fn * 16 + lrow;
      #pragma unroll
      for (int r = 0; r < 4; ++r) {
        const int m = m0 + fm * 16 + quad * 4 + r;
        atomicAdd(&Y[(size_t)m * 512 + n],
                  accH[fm][fn][r] + accL[fm][fn][r] * (1.0f / 4096.0f));
      }
    }
}

// ---------------- Kernel 2: bias+ReLU + 1x1 heads + softmax(6) + decode + ext init ----------------
__global__ __launch_bounds__(64) void heads_decode(
    const float* __restrict__ Yx, const float* __restrict__ Bc,
    const float* __restrict__ Wcls, const float* __restrict__ bcls,
    const float* __restrict__ Wreg, const float* __restrict__ breg,
    float* __restrict__ boxes, float* __restrict__ scores, int* __restrict__ ext)
{
  __shared__ float xs[512];
  const int pos = blockIdx.x;
  const int l = threadIdx.x;
  if (l == 0 && pos < NWORDS) ext[pos] = pos;
  const float* xrow = Yx + (size_t)pos * 512;
  float4 v0 = *(const float4*)&xrow[l * 8];
  float4 v1 = *(const float4*)&xrow[l * 8 + 4];
  const float4 b0 = *(const float4*)&Bc[l * 8];
  const float4 b1 = *(const float4*)&Bc[l * 8 + 4];
  xs[l * 8 + 0] = fmaxf(v0.x + b0.x, 0.f);
  xs[l * 8 + 1] = fmaxf(v0.y + b0.y, 0.f);
  xs[l * 8 + 2] = fmaxf(v0.z + b0.z, 0.f);
  xs[l * 8 + 3] = fmaxf(v0.w + b0.w, 0.f);
  xs[l * 8 + 4] = fmaxf(v1.x + b1.x, 0.f);
  xs[l * 8 + 5] = fmaxf(v1.y + b1.y, 0.f);
  xs[l * 8 + 6] = fmaxf(v1.z + b1.z, 0.f);
  xs[l * 8 + 7] = fmaxf(v1.w + b1.w, 0.f);
  __syncthreads();

  const float* wp;
  int oc;
  float bini;
  if (l < 6)       { wp = Wcls + l;       oc = 6;  bini = bcls[l]; }
  else if (l < 18) { wp = Wreg + (l - 6); oc = 12; bini = breg[l - 6]; }
  else             { wp = Wcls;           oc = 0;  bini = 0.f; }
  float acc = bini;
  const float* p = wp;
  #pragma unroll 4
  for (int c = 0; c < 512; ++c) { acc = fmaf(xs[c], *p, acc); p += oc; }

  const float l0 = __shfl(acc, 0), l1 = __shfl(acc, 1), l2 = __shfl(acc, 2);
  const float l3 = __shfl(acc, 3), l4 = __shfl(acc, 4), l5 = __shfl(acc, 5);
  const int a = (l < 3) ? l : 0;
  const float d0 = __shfl(acc, 6 + a * 4 + 0);
  const float d1 = __shfl(acc, 6 + a * 4 + 1);
  const float d2 = __shfl(acc, 6 + a * 4 + 2);
  const float d3 = __shfl(acc, 6 + a * 4 + 3);

  const float mx = fmaxf(fmaxf(fmaxf(l0, l1), fmaxf(l2, l3)), fmaxf(l4, l5));
  const float e0 = expf(l0 - mx), e1 = expf(l1 - mx), e2 = expf(l2 - mx);
  const float e3 = expf(l3 - mx), e4 = expf(l4 - mx), e5 = expf(l5 - mx);
  const float den = ((((e0 + e1) + e2) + e3) + e4) + e5;
  const float esel = (a == 0) ? e1 : ((a == 1) ? e3 : e5);
  const float sc = esel / den;

  const int px = pos & 63, py = pos >> 6;
  const float cx = (px + 0.5f) * 16.0f;
  const float cy = (py + 0.5f) * 16.0f;
  const float ratio = (a == 0) ? 0.5f : ((a == 1) ? 1.0f : 2.0f);
  const float sq = sqrtf(ratio);
  const float wsz = 128.0f * sq;
  const float hsz = 128.0f / sq;
  const float a0 = cx - wsz * 0.5f;
  const float a1 = cy - hsz * 0.5f;
  const float a2 = cx + wsz * 0.5f;
  const float a3 = cy + hsz * 0.5f;
  const float w = a2 - a0, h = a3 - a1;
  const float xc = __fadd_rn(__fmul_rn(__fadd_rn(a0, a2), 0.5f), __fmul_rn(d0, w));
  const float yc = __fadd_rn(__fmul_rn(__fadd_rn(a1, a3), 0.5f), __fmul_rn(d1, h));
  const float nw = __fmul_rn(w, expf(d2));
  const float nh = __fmul_rn(h, expf(d3));
  float4 box;
  box.x = __fsub_rn(xc, __fmul_rn(nw, 0.5f));
  box.y = __fsub_rn(yc, __fmul_rn(nh, 0.5f));
  box.z = __fadd_rn(xc, __fmul_rn(nw, 0.5f));
  box.w = __fadd_rn(yc, __fmul_rn(nh, 0.5f));

  if (l < 3) {
    const int idx = pos * 3 + a;
    *(float4*)&boxes[idx * 4] = box;
    scores[idx] = sc;
  }
}

// ---------------- Kernel 3: suppression bit-matrix (column-major) + extent ----------------
__global__ __launch_bounds__(256) void build_mask(
    const float* __restrict__ boxes, u64* __restrict__ maskT,
    int* __restrict__ ext)
{
  const int w  = blockIdx.x;
  const int ci = blockIdx.y;
  if (w < ci) return;
  __shared__ float4 rb[64];
  __shared__ int anyf;
  const int t = threadIdx.x;
  const int lane = t & 63, wid = t >> 6;
  if (t == 0) anyf = 0;
  if (t < 64) rb[t] = *(const float4*)&boxes[(ci * 64 + t) * 4];
  const float4 cb = *(const float4*)&boxes[(w * 64 + lane) * 4];
  const float careaa = __fmul_rn(cb.z - cb.x, cb.w - cb.y);
  const int jglob = w * 64 + lane;
  __syncthreads();
  bool any = false;
  for (int rr = 0; rr < 16; ++rr) {
    const int r = wid * 16 + rr;
    const int row = ci * 64 + r;
    const float4 rx = rb[r];
    const float ra = __fmul_rn(rx.z - rx.x, rx.w - rx.y);
    const float xx1 = fmaxf(rx.x, cb.x);
    const float yy1 = fmaxf(rx.y, cb.y);
    const float xx2 = fminf(rx.z, cb.z);
    const float yy2 = fminf(rx.w, cb.w);
    const float iw = fmaxf(__fsub_rn(xx2, xx1), 0.f);
    const float ih = fmaxf(__fsub_rn(yy2, yy1), 0.f);
    const float inter = __fmul_rn(iw, ih);
    const float den = __fadd_rn(__fsub_rn(__fadd_rn(ra, careaa), inter), 1e-9f);
    const float iou = __fdiv_rn(inter, den);
    const bool bit = (iou > NMS_THRESH) && (jglob > row);
    any |= bit;
    const u64 word = __ballot(bit ? 1 : 0);
    if (lane == 0) maskT[(size_t)w * NBOX + row] = word;
  }
  if (any) anyf = 1;
  __syncthreads();
  if (t == 0 && anyf && w > ci) atomicMax(&ext[ci], w);
}

// ---------------- Kernel 4: sequential greedy NMS scan (v10 = v4 + S-ballot) ----------------
// v4 (316us, best measured): 4 waves, per-wave-replicated scalar greedy resolve, LDS
// alive + atomicAnd, one raw barrier per step, 1-deep register prefetch.
// v10 adds the S-ballot fast path: S = {b alive : dg[b] & aw0 != 0} (bits that can
// suppress something alive in-word). Chain runs over S only -- usually empty, so the
// ~10-round / ~1300cy chain collapses to a ballot + test. Exact: non-S bits suppress
// nothing alive; bits suppressed by accepted S-bits are stripped from aw via supp.
__device__ __forceinline__ u64 rl64(unsigned lo, unsigned hi, int l) {
  const unsigned a = (unsigned)__builtin_amdgcn_readlane((int)lo, l);
  const unsigned b = (unsigned)__builtin_amdgcn_readlane((int)hi, l);
  return ((u64)b << 32) | (u64)a;
}

__global__ __launch_bounds__(256) void nms_scan(
    const float* __restrict__ scores, const u64* __restrict__ maskT,
    const int* __restrict__ ext, u64* __restrict__ aliveOut)
{
  __shared__ u64 alive[NWORDS];
  __shared__ int extS[NWORDS];
  const int t = threadIdx.x;
  const int lane = t & 63;
  const int wsub = t >> 3;   // 0..31: which downstream word this thread serves
  const int sub = t & 7;     // which 8-row octet of that word's column
  if (t < NWORDS) {
    u64 wbits = 0ull;
    const float4* sp = (const float4*)(scores + t * 64);
    #pragma unroll
    for (int q = 0; q < 16; ++q) {
      const float4 s = sp[q];
      if (s.x > POS_THRESH) wbits |= (1ull << (q * 4 + 0));
      if (s.y > POS_THRESH) wbits |= (1ull << (q * 4 + 1));
      if (s.z > POS_THRESH) wbits |= (1ull << (q * 4 + 2));
      if (s.w > POS_THRESH) wbits |= (1ull << (q * 4 + 3));
    }
    alive[t] = wbits;
    extS[t] = ext[t];
  }
  // register pipeline preload for c = 0 (stays in flight across the init barrier)
  u64 mA[8], mB[8];
  #pragma unroll
  for (int j = 0; j < 8; ++j) { mA[j] = 0ull; mB[j] = 0ull; }
  const int e0 = ext[0];
  if (1 + wsub <= e0) {
    const u64* cbp = maskT + (size_t)(1 + wsub) * NBOX + sub * 8;
    #pragma unroll
    for (int j = 0; j < 8; ++j) mA[j] = cbp[j];
  }
  u64 dg = maskT[lane];   // diagonal block (0,0), row = lane
  asm volatile("s_waitcnt lgkmcnt(0)" ::: "memory");
  __builtin_amdgcn_s_barrier();
  asm volatile("" ::: "memory");

  for (int c = 0; c < NWORDS; ++c) {
    const int e = extS[c];
    const u64 aw0v = alive[c];
    // ---- prefetch for iteration c+1 (addresses independent of this iteration) ----
    u64 dgn = 0ull;
    if (c + 1 < NWORDS) {
      dgn = maskT[(size_t)(c + 1) * NBOX + (size_t)(c + 1) * 64 + lane];
      const int en = extS[c + 1];
      const int t0n = c + 2 + wsub;
      if (t0n <= en) {
        const u64* cbp = maskT + (size_t)t0n * NBOX + (size_t)(c + 1) * 64 + sub * 8;
        #pragma unroll
        for (int j = 0; j < 8; ++j) mB[j] = cbp[j];
      }
    }
    // ---- phase A: S-ballot fast path + scalar greedy resolve (replicated/wave) ----
    const unsigned awlo = (unsigned)__builtin_amdgcn_readfirstlane((int)(unsigned)(aw0v & 0xffffffffull));
    const unsigned awhi = (unsigned)__builtin_amdgcn_readfirstlane((int)(unsigned)(aw0v >> 32));
    const u64 aw0 = ((u64)awhi << 32) | (u64)awlo;
    if (aw0) {
      const unsigned dlo = (unsigned)(dg & 0xffffffffull);
      const unsigned dhi = (unsigned)(dg >> 32);
      u64 aw = aw0;
      // S-ballot: bits that can suppress something alive in this word
      const bool sb = ((aw0 >> lane) & 1ull) && ((dg & aw0) != 0ull);
      u64 pending = __ballot(sb ? 1 : 0);
      while (pending) {
        const u64 p0 = pending;
        const u64 p1 = p0 & (p0 - 1);
        const u64 p2 = p1 & (p1 - 1);
        const u64 p3 = p2 & (p2 - 1);
        const int b0 = __builtin_ctzll(p0);
        const int b1 = p1 ? __builtin_ctzll(p1) : 64;
        const int b2 = p2 ? __builtin_ctzll(p2) : 64;
        const int b3 = p3 ? __builtin_ctzll(p3) : 64;
        const u64 r0 = rl64(dlo, dhi, b0);
        const u64 r1 = rl64(dlo, dhi, b1 & 63);
        const u64 r2 = rl64(dlo, dhi, b2 & 63);
        const u64 r3 = rl64(dlo, dhi, b3 & 63);
        u64 supp = r0;
        u64 done = 1ull << b0;
        // speculative accepts, in order, exact greedy semantics:
        const u64 k1 = ((b1 < 64) & !((supp >> (b1 & 63)) & 1ull)) ? ~0ull : 0ull;
        supp |= r1 & k1;  done |= (1ull << (b1 & 63)) & k1;
        const u64 k2 = ((b2 < 64) & !((supp >> (b2 & 63)) & 1ull)) ? ~0ull : 0ull;
        supp |= r2 & k2;  done |= (1ull << (b2 & 63)) & k2;
        const u64 k3 = ((b3 < 64) & !((supp >> (b3 & 63)) & 1ull)) ? ~0ull : 0ull;
        supp |= r3 & k3;  done |= (1ull << (b3 & 63)) & k3;
        aw &= ~supp;
        pending &= ~(supp | done);
      }
      // ---- phase B: per-lane select from prefetched column block + LDS atomicAnd ----
      const int t0 = c + 1 + wsub;
      if (t0 <= e) {
        const unsigned oct = (unsigned)(aw >> (sub * 8)) & 0xffu;
        u64 sup = 0ull;
        #pragma unroll
        for (int j = 0; j < 8; ++j) if ((oct >> j) & 1u) sup |= mA[j];
        if (sup) atomicAnd((unsigned long long*)&alive[t0], ~sup);
      }
      // rare overflow passes when the extent spans more than 32 words
      for (int base = c + 33; base <= e; base += 32) {
        const int tw = base + wsub;
        if (tw <= e) {
          const u64* cbp = maskT + (size_t)tw * NBOX + (size_t)c * 64 + sub * 8;
          u64 m[8];
          #pragma unroll
          for (int j = 0; j < 8; ++j) m[j] = cbp[j];
          const unsigned oct = (unsigned)(aw >> (sub * 8)) & 0xffu;
          u64 sup = 0ull;
          #pragma unroll
          for (int j = 0; j < 8; ++j) if ((oct >> j) & 1u) sup |= m[j];
          if (sup) atomicAnd((unsigned long long*)&alive[tw], ~sup);
        }
      }
      if (t == 0) alive[c] = aw;
    }
    // rotate the register pipeline
    dg = dgn;
    #pragma unroll
    for (int j = 0; j < 8; ++j) mA[j] = mB[j];
    // raw barrier: drain LDS ops only; global prefetches stay in flight
    asm volatile("s_waitcnt lgkmcnt(0)" ::: "memory");
    __builtin_amdgcn_s_barrier();
    asm volatile("" ::: "memory");
  }
  if (t < NWORDS) aliveOut[t] = alive[t];
}

// ---------------- Kernel 5: masked output ----------------
__global__ __launch_bounds__(256) void write_output(
    const float* __restrict__ boxes, const u64* __restrict__ alive,
    float* __restrict__ out)
{
  const int i = blockIdx.x * 256 + threadIdx.x;
  if (i < NBOX) {
    const bool k = (alive[i >> 6] >> (i & 63)) & 1ull;
    const float4 b = *(const float4*)&boxes[i * 4];
    const float4 z = {0.f, 0.f, 0.f, 0.f};
    *(float4*)&out[i * 4] = k ? b : z;
  }
}

extern "C" void kernel_launch(void* const* d_in, const int* in_sizes, int n_in,
                              void* d_out, int out_size, void* d_ws, size_t ws_size,
                              hipStream_t stream) {
  const float* X    = (const float*)d_in[0];  // (1,64,64,1024)
  const float* Wc   = (const float*)d_in[1];  // (3,3,1024,512)
  const float* Bc   = (const float*)d_in[2];  // (512,)
  const float* Wcls = (const float*)d_in[3];  // (1,1,512,6)
  const float* bcls = (const float*)d_in[4];  // (6,)
  const float* Wreg = (const float*)d_in[5];  // (1,1,512,12)
  const float* breg = (const float*)d_in[6];  // (12,)

  char* ws = (char*)d_ws;
  float*     Y      = (float*)    (ws);                 // 8,388,608 B (raw conv sums)
  float*     boxes  = (float*)    (ws + 8388608);       //   196,608 B
  float*     scores = (float*)    (ws + 8585216);       //    49,152 B
  u64*       aliveG = (u64*)      (ws + 8634368);       //     1,536 B
  int*       extG   = (int*)      (ws + 8635904);       //       768 B
  // conv phase uses [8,636,672 .. 27,511,040) for WTh+WTl; maskT reuses the
  // SAME region after conv is done (both exactly 18,874,368 B).
  _Float16*  WTh    = (_Float16*) (ws + 8636672);       // 9,437,184 B
  _Float16*  WTl    = (_Float16*) (ws + 18073856);      // 9,437,184 B
  u64*       maskT  = (u64*)      (ws + 8636672);       // 18,874,368 B (post-conv)

  zero_y      <<<2048, 256, 0, stream>>>((float4*)Y);
  prep_wt     <<<1152, 256, 0, stream>>>(Wc, WTh, WTl);
  conv_mfma   <<<256, 256, 0, stream>>>(X, WTh, WTl, Y);
  heads_decode<<<4096, 64, 0, stream>>>(Y, Bc, Wcls, bcls, Wreg, breg, boxes, scores, extG);
  build_mask  <<<dim3(192, 192), 256, 0, stream>>>(boxes, maskT, extG);
  nms_scan    <<<1, 256, 0, stream>>>(scores, maskT, extG, aliveG);
  write_output<<<48, 256, 0, stream>>>(boxes, aliveG, (float*)d_out);
}

// Round 10
// 529.253 us; speedup vs baseline: 1.5864x; 1.1563x over previous
//
#include <hip/hip_runtime.h>
#include <cstdint>

#define NBOX 12288
#define NWORDS 192
#define POS_THRESH 0.15f
#define NMS_THRESH 0.7f

typedef unsigned long long u64;
typedef _Float16 half8 __attribute__((ext_vector_type(8)));
typedef float floatx4 __attribute__((ext_vector_type(4)));

// ---------------- Kernel 0a: zero the conv accumulator ----------------
__global__ __launch_bounds__(256) void zero_y(float4* __restrict__ Y) {
  Y[blockIdx.x * 256 + threadIdx.x] = float4{0.f, 0.f, 0.f, 0.f};
}

// ---------------- Kernel 0b: W (3,3,1024,512) -> WT[tap][n][c] fp16 h/l split ----------------
// l pre-scaled by 4096 so it stays in fp16 normal range (w~0.01 -> wl~2e-6 would be denormal).
__global__ __launch_bounds__(256) void prep_wt(
    const float* __restrict__ Wc, _Float16* __restrict__ WTh, _Float16* __restrict__ WTl)
{
  __shared__ float tile[64][65];
  const int b = blockIdx.x;           // 9 taps * 16 c-tiles * 8 n-tiles = 1152
  const int tap = b >> 7;
  const int rem = b & 127;
  const int c0 = (rem >> 3) * 64, n0 = (rem & 7) * 64;
  const int t = threadIdx.x;
  #pragma unroll
  for (int i = 0; i < 16; ++i) {
    const int idx = i * 256 + t;
    const int c = idx >> 6, n = idx & 63;
    tile[n][c] = Wc[((size_t)(tap * 1024 + c0 + c)) * 512 + n0 + n];
  }
  __syncthreads();
  #pragma unroll
  for (int i = 0; i < 16; ++i) {
    const int idx = i * 256 + t;
    const int n = idx >> 6, c = idx & 63;
    const float v = tile[n][c];
    const _Float16 h = (_Float16)v;
    const _Float16 l = (_Float16)((v - (float)h) * 4096.0f);
    const size_t o = ((size_t)(tap * 512 + n0 + n)) * 1024 + c0 + c;
    WTh[o] = h;
    WTl[o] = l;
  }
}

// ---------------- Kernel 1: 3x3 conv via split-fp16 MFMA ----------------
// v11: (1) 4 K-slices (256ch each) -> grid 512 -> 2 blocks/CU (was 1): TLP hides
// barrier + B-stage global latency (was 1 wave/SIMD, 160 exposed barriers/block).
// (2) LDS 16B-slot XOR swizzle key=(row>>3)&3: AROW=40 (20 words) has bank period 8,
// so rows r/r+8 collided 8-way on ds_write_b128 (9.4M conflict cycles). Swizzle makes
// all staging writes + fragment reads <=2-way (free).
#define AROW 40                 // 32 k-halves padded to 40
#define AS_PLANE (4 * 66 * AROW)
#define BS_PLANE (128 * AROW)
__global__ __launch_bounds__(256, 2) void conv_mfma(
    const float* __restrict__ X, const _Float16* __restrict__ WTh,
    const _Float16* __restrict__ WTl, float* __restrict__ Y)
{
  __shared__ _Float16 As[2 * AS_PLANE];   // 42,240 B
  __shared__ _Float16 Bs[2 * BS_PLANE];   // 20,480 B
  const int bid = blockIdx.x;
  const int ks = bid & 3;                 // 4 K-slices of 256 ch
  const int nt = (bid >> 2) & 3;
  const int mt = bid >> 4;
  const int t = threadIdx.x;
  const int lane = t & 63, wid = t >> 6;
  const int wm = wid >> 1, wn = wid & 1;
  const int lrow = lane & 15, quad = lane >> 4;

  floatx4 accH[4][4], accL[4][4];
  #pragma unroll
  for (int i = 0; i < 4; ++i)
    #pragma unroll
    for (int j = 0; j < 4; ++j) { accH[i][j] = (floatx4)0.f; accL[i][j] = (floatx4)0.f; }

  for (int kc = 0; kc < 8; ++kc) {
    const int c0 = ks * 256 + kc * 32;
    __syncthreads();   // prior chunk readers done
    // ---- stage A halo: 264 (yy,xx) rows x 32 ch, split to h/l, slot-swizzled ----
    for (int r = t; r < 264; r += 256) {
      const int yy = r / 66;
      const int xx = r - yy * 66;
      const int yi = mt * 2 + yy - 1;
      const int xi = xx - 1;
      const int akey = (r >> 3) & 3;
      _Float16* dsth = &As[r * AROW];
      _Float16* dstl = dsth + AS_PLANE;
      if (yi >= 0 && yi < 64 && xi >= 0 && xi < 64) {
        const float4* src = (const float4*)(X + ((size_t)(yi * 64 + xi)) * 1024 + c0);
        #pragma unroll
        for (int j = 0; j < 4; ++j) {
          const float4 va = src[2 * j], vb = src[2 * j + 1];
          const float f[8] = {va.x, va.y, va.z, va.w, vb.x, vb.y, vb.z, vb.w};
          half8 hh, hl;
          #pragma unroll
          for (int e = 0; e < 8; ++e) {
            const _Float16 h = (_Float16)f[e];
            hh[e] = h;
            hl[e] = (_Float16)((f[e] - (float)h) * 4096.0f);
          }
          const int sl = (j ^ akey) * 8;
          *(half8*)&dsth[sl] = hh;
          *(half8*)&dstl[sl] = hl;
        }
      } else {
        const half8 z = (half8)(_Float16)0.f;
        #pragma unroll
        for (int j = 0; j < 4; ++j) { *(half8*)&dsth[j * 8] = z; *(half8*)&dstl[j * 8] = z; }
      }
    }
    for (int tap = 0; tap < 9; ++tap) {
      if (tap > 0) __syncthreads();   // prior tap's B readers done
      {   // ---- stage B: 256 rows (hl,n) x 32 halves, slot-swizzled ----
        const int hl = t >> 7, n = t & 127;
        const int bkey = (n >> 3) & 3;
        const _Float16* src = (hl ? WTl : WTh) +
            ((size_t)(tap * 512 + nt * 128 + n)) * 1024 + c0;
        _Float16* dst = &Bs[hl * BS_PLANE + n * AROW];
        #pragma unroll
        for (int j = 0; j < 4; ++j)
          *(half8*)&dst[(j ^ bkey) * 8] = *(const half8*)&src[j * 8];
      }
      __syncthreads();   // A (first tap) + B visible
      const int dy = tap / 3 - 1, dx = tap - (tap / 3) * 3 - 1;
      const int yy = wm + dy + 1;
      const int xxb = dx + 1;
      half8 Ah[4], Al[4], Bh[4], Bl[4];
      #pragma unroll
      for (int fm = 0; fm < 4; ++fm) {
        const int row = yy * 66 + xxb + fm * 16 + lrow;
        const int idx = row * AROW + ((quad ^ ((row >> 3) & 3)) * 8);
        Ah[fm] = *(const half8*)&As[idx];
        Al[fm] = *(const half8*)&As[idx + AS_PLANE];
      }
      #pragma unroll
      for (int fn = 0; fn < 4; ++fn) {
        const int row = wn * 64 + fn * 16 + lrow;
        const int idx = row * AROW + ((quad ^ ((row >> 3) & 3)) * 8);
        Bh[fn] = *(const half8*)&Bs[idx];
        Bl[fn] = *(const half8*)&Bs[idx + BS_PLANE];
      }
      #pragma unroll
      for (int fm = 0; fm < 4; ++fm)
        #pragma unroll
        for (int fn = 0; fn < 4; ++fn) {
          accH[fm][fn] = __builtin_amdgcn_mfma_f32_16x16x32_f16(Ah[fm], Bh[fn], accH[fm][fn], 0, 0, 0);
          accL[fm][fn] = __builtin_amdgcn_mfma_f32_16x16x32_f16(Al[fm], Bh[fn], accL[fm][fn], 0, 0, 0);
          accL[fm][fn] = __builtin_amdgcn_mfma_f32_16x16x32_f16(Ah[fm], Bl[fn], accL[fm][fn], 0, 0, 0);
        }
    }
  }
  // ---- epilogue: combine scales, atomic-accumulate (4 K-slices per output) ----
  const int m0 = mt * 128 + wm * 64;
  const int n0 = nt * 128 + wn * 64;
  #pragma unroll
  for (int fm = 0; fm < 4; ++fm)
    #pragma unroll
    for (int fn = 0; fn < 4; ++fn) {
      const int n = n0 + fn * 16 + lrow;
      #pragma unroll
      for (int r = 0; r < 4; ++r) {
        const int m = m0 + fm * 16 + quad * 4 + r;
        atomicAdd(&Y[(size_t)m * 512 + n],
                  accH[fm][fn][r] + accL[fm][fn][r] * (1.0f / 4096.0f));
      }
    }
}

// ---------------- Kernel 2: bias+ReLU + 1x1 heads + softmax(6) + decode + ext init ----------------
__global__ __launch_bounds__(64) void heads_decode(
    const float* __restrict__ Yx, const float* __restrict__ Bc,
    const float* __restrict__ Wcls, const float* __restrict__ bcls,
    const float* __restrict__ Wreg, const float* __restrict__ breg,
    float* __restrict__ boxes, float* __restrict__ scores, int* __restrict__ ext)
{
  __shared__ float xs[512];
  const int pos = blockIdx.x;
  const int l = threadIdx.x;
  if (l == 0 && pos < NWORDS) ext[pos] = pos;
  const float* xrow = Yx + (size_t)pos * 512;
  float4 v0 = *(const float4*)&xrow[l * 8];
  float4 v1 = *(const float4*)&xrow[l * 8 + 4];
  const float4 b0 = *(const float4*)&Bc[l * 8];
  const float4 b1 = *(const float4*)&Bc[l * 8 + 4];
  xs[l * 8 + 0] = fmaxf(v0.x + b0.x, 0.f);
  xs[l * 8 + 1] = fmaxf(v0.y + b0.y, 0.f);
  xs[l * 8 + 2] = fmaxf(v0.z + b0.z, 0.f);
  xs[l * 8 + 3] = fmaxf(v0.w + b0.w, 0.f);
  xs[l * 8 + 4] = fmaxf(v1.x + b1.x, 0.f);
  xs[l * 8 + 5] = fmaxf(v1.y + b1.y, 0.f);
  xs[l * 8 + 6] = fmaxf(v1.z + b1.z, 0.f);
  xs[l * 8 + 7] = fmaxf(v1.w + b1.w, 0.f);
  __syncthreads();

  const float* wp;
  int oc;
  float bini;
  if (l < 6)       { wp = Wcls + l;       oc = 6;  bini = bcls[l]; }
  else if (l < 18) { wp = Wreg + (l - 6); oc = 12; bini = breg[l - 6]; }
  else             { wp = Wcls;           oc = 0;  bini = 0.f; }
  float acc = bini;
  const float* p = wp;
  #pragma unroll 4
  for (int c = 0; c < 512; ++c) { acc = fmaf(xs[c], *p, acc); p += oc; }

  const float l0 = __shfl(acc, 0), l1 = __shfl(acc, 1), l2 = __shfl(acc, 2);
  const float l3 = __shfl(acc, 3), l4 = __shfl(acc, 4), l5 = __shfl(acc, 5);
  const int a = (l < 3) ? l : 0;
  const float d0 = __shfl(acc, 6 + a * 4 + 0);
  const float d1 = __shfl(acc, 6 + a * 4 + 1);
  const float d2 = __shfl(acc, 6 + a * 4 + 2);
  const float d3 = __shfl(acc, 6 + a * 4 + 3);

  const float mx = fmaxf(fmaxf(fmaxf(l0, l1), fmaxf(l2, l3)), fmaxf(l4, l5));
  const float e0 = expf(l0 - mx), e1 = expf(l1 - mx), e2 = expf(l2 - mx);
  const float e3 = expf(l3 - mx), e4 = expf(l4 - mx), e5 = expf(l5 - mx);
  const float den = ((((e0 + e1) + e2) + e3) + e4) + e5;
  const float esel = (a == 0) ? e1 : ((a == 1) ? e3 : e5);
  const float sc = esel / den;

  const int px = pos & 63, py = pos >> 6;
  const float cx = (px + 0.5f) * 16.0f;
  const float cy = (py + 0.5f) * 16.0f;
  const float ratio = (a == 0) ? 0.5f : ((a == 1) ? 1.0f : 2.0f);
  const float sq = sqrtf(ratio);
  const float wsz = 128.0f * sq;
  const float hsz = 128.0f / sq;
  const float a0 = cx - wsz * 0.5f;
  const float a1 = cy - hsz * 0.5f;
  const float a2 = cx + wsz * 0.5f;
  const float a3 = cy + hsz * 0.5f;
  const float w = a2 - a0, h = a3 - a1;
  const float xc = __fadd_rn(__fmul_rn(__fadd_rn(a0, a2), 0.5f), __fmul_rn(d0, w));
  const float yc = __fadd_rn(__fmul_rn(__fadd_rn(a1, a3), 0.5f), __fmul_rn(d1, h));
  const float nw = __fmul_rn(w, expf(d2));
  const float nh = __fmul_rn(h, expf(d3));
  float4 box;
  box.x = __fsub_rn(xc, __fmul_rn(nw, 0.5f));
  box.y = __fsub_rn(yc, __fmul_rn(nh, 0.5f));
  box.z = __fadd_rn(xc, __fmul_rn(nw, 0.5f));
  box.w = __fadd_rn(yc, __fmul_rn(nh, 0.5f));

  if (l < 3) {
    const int idx = pos * 3 + a;
    *(float4*)&boxes[idx * 4] = box;
    scores[idx] = sc;
  }
}

// ---------------- Kernel 3: suppression bit-matrix (column-major) + extent ----------------
__global__ __launch_bounds__(256) void build_mask(
    const float* __restrict__ boxes, u64* __restrict__ maskT,
    int* __restrict__ ext)
{
  const int w  = blockIdx.x;
  const int ci = blockIdx.y;
  if (w < ci) return;
  __shared__ float4 rb[64];
  __shared__ int anyf;
  const int t = threadIdx.x;
  const int lane = t & 63, wid = t >> 6;
  if (t == 0) anyf = 0;
  if (t < 64) rb[t] = *(const float4*)&boxes[(ci * 64 + t) * 4];
  const float4 cb = *(const float4*)&boxes[(w * 64 + lane) * 4];
  const float careaa = __fmul_rn(cb.z - cb.x, cb.w - cb.y);
  const int jglob = w * 64 + lane;
  __syncthreads();
  bool any = false;
  for (int rr = 0; rr < 16; ++rr) {
    const int r = wid * 16 + rr;
    const int row = ci * 64 + r;
    const float4 rx = rb[r];
    const float ra = __fmul_rn(rx.z - rx.x, rx.w - rx.y);
    const float xx1 = fmaxf(rx.x, cb.x);
    const float yy1 = fmaxf(rx.y, cb.y);
    const float xx2 = fminf(rx.z, cb.z);
    const float yy2 = fminf(rx.w, cb.w);
    const float iw = fmaxf(__fsub_rn(xx2, xx1), 0.f);
    const float ih = fmaxf(__fsub_rn(yy2, yy1), 0.f);
    const float inter = __fmul_rn(iw, ih);
    const float den = __fadd_rn(__fsub_rn(__fadd_rn(ra, careaa), inter), 1e-9f);
    const float iou = __fdiv_rn(inter, den);
    const bool bit = (iou > NMS_THRESH) && (jglob > row);
    any |= bit;
    const u64 word = __ballot(bit ? 1 : 0);
    if (lane == 0) maskT[(size_t)w * NBOX + row] = word;
  }
  if (any) anyf = 1;
  __syncthreads();
  if (t == 0 && anyf && w > ci) atomicMax(&ext[ci], w);
}

// ---------------- Kernel 4: sequential greedy NMS scan (v10 = v4 + S-ballot) ----------------
__device__ __forceinline__ u64 rl64(unsigned lo, unsigned hi, int l) {
  const unsigned a = (unsigned)__builtin_amdgcn_readlane((int)lo, l);
  const unsigned b = (unsigned)__builtin_amdgcn_readlane((int)hi, l);
  return ((u64)b << 32) | (u64)a;
}

__global__ __launch_bounds__(256) void nms_scan(
    const float* __restrict__ scores, const u64* __restrict__ maskT,
    const int* __restrict__ ext, u64* __restrict__ aliveOut)
{
  __shared__ u64 alive[NWORDS];
  __shared__ int extS[NWORDS];
  const int t = threadIdx.x;
  const int lane = t & 63;
  const int wsub = t >> 3;   // 0..31: which downstream word this thread serves
  const int sub = t & 7;     // which 8-row octet of that word's column
  if (t < NWORDS) {
    u64 wbits = 0ull;
    const float4* sp = (const float4*)(scores + t * 64);
    #pragma unroll
    for (int q = 0; q < 16; ++q) {
      const float4 s = sp[q];
      if (s.x > POS_THRESH) wbits |= (1ull << (q * 4 + 0));
      if (s.y > POS_THRESH) wbits |= (1ull << (q * 4 + 1));
      if (s.z > POS_THRESH) wbits |= (1ull << (q * 4 + 2));
      if (s.w > POS_THRESH) wbits |= (1ull << (q * 4 + 3));
    }
    alive[t] = wbits;
    extS[t] = ext[t];
  }
  // register pipeline preload for c = 0 (stays in flight across the init barrier)
  u64 mA[8], mB[8];
  #pragma unroll
  for (int j = 0; j < 8; ++j) { mA[j] = 0ull; mB[j] = 0ull; }
  const int e0 = ext[0];
  if (1 + wsub <= e0) {
    const u64* cbp = maskT + (size_t)(1 + wsub) * NBOX + sub * 8;
    #pragma unroll
    for (int j = 0; j < 8; ++j) mA[j] = cbp[j];
  }
  u64 dg = maskT[lane];   // diagonal block (0,0), row = lane
  asm volatile("s_waitcnt lgkmcnt(0)" ::: "memory");
  __builtin_amdgcn_s_barrier();
  asm volatile("" ::: "memory");

  for (int c = 0; c < NWORDS; ++c) {
    const int e = extS[c];
    const u64 aw0v = alive[c];
    // ---- prefetch for iteration c+1 (addresses independent of this iteration) ----
    u64 dgn = 0ull;
    if (c + 1 < NWORDS) {
      dgn = maskT[(size_t)(c + 1) * NBOX + (size_t)(c + 1) * 64 + lane];
      const int en = extS[c + 1];
      const int t0n = c + 2 + wsub;
      if (t0n <= en) {
        const u64* cbp = maskT + (size_t)t0n * NBOX + (size_t)(c + 1) * 64 + sub * 8;
        #pragma unroll
        for (int j = 0; j < 8; ++j) mB[j] = cbp[j];
      }
    }
    // ---- phase A: S-ballot fast path + scalar greedy resolve (replicated/wave) ----
    const unsigned awlo = (unsigned)__builtin_amdgcn_readfirstlane((int)(unsigned)(aw0v & 0xffffffffull));
    const unsigned awhi = (unsigned)__builtin_amdgcn_readfirstlane((int)(unsigned)(aw0v >> 32));
    const u64 aw0 = ((u64)awhi << 32) | (u64)awlo;
    if (aw0) {
      const unsigned dlo = (unsigned)(dg & 0xffffffffull);
      const unsigned dhi = (unsigned)(dg >> 32);
      u64 aw = aw0;
      // S-ballot: bits that can suppress something alive in this word
      const bool sb = ((aw0 >> lane) & 1ull) && ((dg & aw0) != 0ull);
      u64 pending = __ballot(sb ? 1 : 0);
      while (pending) {
        const u64 p0 = pending;
        const u64 p1 = p0 & (p0 - 1);
        const u64 p2 = p1 & (p1 - 1);
        const u64 p3 = p2 & (p2 - 1);
        const int b0 = __builtin_ctzll(p0);
        const int b1 = p1 ? __builtin_ctzll(p1) : 64;
        const int b2 = p2 ? __builtin_ctzll(p2) : 64;
        const int b3 = p3 ? __builtin_ctzll(p3) : 64;
        const u64 r0 = rl64(dlo, dhi, b0);
        const u64 r1 = rl64(dlo, dhi, b1 & 63);
        const u64 r2 = rl64(dlo, dhi, b2 & 63);
        const u64 r3 = rl64(dlo, dhi, b3 & 63);
        u64 supp = r0;
        u64 done = 1ull << b0;
        // speculative accepts, in order, exact greedy semantics:
        const u64 k1 = ((b1 < 64) & !((supp >> (b1 & 63)) & 1ull)) ? ~0ull : 0ull;
        supp |= r1 & k1;  done |= (1ull << (b1 & 63)) & k1;
        const u64 k2 = ((b2 < 64) & !((supp >> (b2 & 63)) & 1ull)) ? ~0ull : 0ull;
        supp |= r2 & k2;  done |= (1ull << (b2 & 63)) & k2;
        const u64 k3 = ((b3 < 64) & !((supp >> (b3 & 63)) & 1ull)) ? ~0ull : 0ull;
        supp |= r3 & k3;  done |= (1ull << (b3 & 63)) & k3;
        aw &= ~supp;
        pending &= ~(supp | done);
      }
      // ---- phase B: per-lane select from prefetched column block + LDS atomicAnd ----
      const int t0 = c + 1 + wsub;
      if (t0 <= e) {
        const unsigned oct = (unsigned)(aw >> (sub * 8)) & 0xffu;
        u64 sup = 0ull;
        #pragma unroll
        for (int j = 0; j < 8; ++j) if ((oct >> j) & 1u) sup |= mA[j];
        if (sup) atomicAnd((unsigned long long*)&alive[t0], ~sup);
      }
      // rare overflow passes when the extent spans more than 32 words
      for (int base = c + 33; base <= e; base += 32) {
        const int tw = base + wsub;
        if (tw <= e) {
          const u64* cbp = maskT + (size_t)tw * NBOX + (size_t)c * 64 + sub * 8;
          u64 m[8];
          #pragma unroll
          for (int j = 0; j < 8; ++j) m[j] = cbp[j];
          const unsigned oct = (unsigned)(aw >> (sub * 8)) & 0xffu;
          u64 sup = 0ull;
          #pragma unroll
          for (int j = 0; j < 8; ++j) if ((oct >> j) & 1u) sup |= m[j];
          if (sup) atomicAnd((unsigned long long*)&alive[tw], ~sup);
        }
      }
      if (t == 0) alive[c] = aw;
    }
    // rotate the register pipeline
    dg = dgn;
    #pragma unroll
    for (int j = 0; j < 8; ++j) mA[j] = mB[j];
    // raw barrier: drain LDS ops only; global prefetches stay in flight
    asm volatile("s_waitcnt lgkmcnt(0)" ::: "memory");
    __builtin_amdgcn_s_barrier();
    asm volatile("" ::: "memory");
  }
  if (t < NWORDS) aliveOut[t] = alive[t];
}

// ---------------- Kernel 5: masked output ----------------
__global__ __launch_bounds__(256) void write_output(
    const float* __restrict__ boxes, const u64* __restrict__ alive,
    float* __restrict__ out)
{
  const int i = blockIdx.x * 256 + threadIdx.x;
  if (i < NBOX) {
    const bool k = (alive[i >> 6] >> (i & 63)) & 1ull;
    const float4 b = *(const float4*)&boxes[i * 4];
    const float4 z = {0.f, 0.f, 0.f, 0.f};
    *(float4*)&out[i * 4] = k ? b : z;
  }
}

extern "C" void kernel_launch(void* const* d_in, const int* in_sizes, int n_in,
                              void* d_out, int out_size, void* d_ws, size_t ws_size,
                              hipStream_t stream) {
  const float* X    = (const float*)d_in[0];  // (1,64,64,1024)
  const float* Wc   = (const float*)d_in[1];  // (3,3,1024,512)
  const float* Bc   = (const float*)d_in[2];  // (512,)
  const float* Wcls = (const float*)d_in[3];  // (1,1,512,6)
  const float* bcls = (const float*)d_in[4];  // (6,)
  const float* Wreg = (const float*)d_in[5];  // (1,1,512,12)
  const float* breg = (const float*)d_in[6];  // (12,)

  char* ws = (char*)d_ws;
  float*     Y      = (float*)    (ws);                 // 8,388,608 B (raw conv sums)
  float*     boxes  = (float*)    (ws + 8388608);       //   196,608 B
  float*     scores = (float*)    (ws + 8585216);       //    49,152 B
  u64*       aliveG = (u64*)      (ws + 8634368);       //     1,536 B
  int*       extG   = (int*)      (ws + 8635904);       //       768 B
  // conv phase uses [8,636,672 .. 27,511,040) for WTh+WTl; maskT reuses the
  // SAME region after conv is done (both exactly 18,874,368 B).
  _Float16*  WTh    = (_Float16*) (ws + 8636672);       // 9,437,184 B
  _Float16*  WTl    = (_Float16*) (ws + 18073856);      // 9,437,184 B
  u64*       maskT  = (u64*)      (ws + 8636672);       // 18,874,368 B (post-conv)

  zero_y      <<<2048, 256, 0, stream>>>((float4*)Y);
  prep_wt     <<<1152, 256, 0, stream>>>(Wc, WTh, WTl);
  conv_mfma   <<<512, 256, 0, stream>>>(X, WTh, WTl, Y);
  heads_decode<<<4096, 64, 0, stream>>>(Y, Bc, Wcls, bcls, Wreg, breg, boxes, scores, extG);
  build_mask  <<<dim3(192, 192), 256, 0, stream>>>(boxes, maskT, extG);
  nms_scan    <<<1, 256, 0, stream>>>(scores, maskT, extG, aliveG);
  write_output<<<48, 256, 0, stream>>>(boxes, aliveG, (float*)d_out);
}

// Round 11
// 511.734 us; speedup vs baseline: 1.6407x; 1.0342x over previous
//
#include <hip/hip_runtime.h>
#include <cstdint>

#define NBOX 12288
#define NWORDS 192
#define POS_THRESH 0.15f
#define NMS_THRESH 0.7f

typedef unsigned long long u64;
typedef _Float16 half8 __attribute__((ext_vector_type(8)));
typedef float floatx4 __attribute__((ext_vector_type(4)));

// ---------------- Kernel 0a: zero the conv accumulator ----------------
__global__ __launch_bounds__(256) void zero_y(float4* __restrict__ Y) {
  Y[blockIdx.x * 256 + threadIdx.x] = float4{0.f, 0.f, 0.f, 0.f};
}

// ---------------- Kernel 0b: W (3,3,1024,512) -> WT[tap][n][c] fp16 h/l split ----------------
// l pre-scaled by 4096 so it stays in fp16 normal range (w~0.01 -> wl~2e-6 would be denormal).
__global__ __launch_bounds__(256) void prep_wt(
    const float* __restrict__ Wc, _Float16* __restrict__ WTh, _Float16* __restrict__ WTl)
{
  __shared__ float tile[64][65];
  const int b = blockIdx.x;           // 9 taps * 16 c-tiles * 8 n-tiles = 1152
  const int tap = b >> 7;
  const int rem = b & 127;
  const int c0 = (rem >> 3) * 64, n0 = (rem & 7) * 64;
  const int t = threadIdx.x;
  #pragma unroll
  for (int i = 0; i < 16; ++i) {
    const int idx = i * 256 + t;
    const int c = idx >> 6, n = idx & 63;
    tile[n][c] = Wc[((size_t)(tap * 1024 + c0 + c)) * 512 + n0 + n];
  }
  __syncthreads();
  #pragma unroll
  for (int i = 0; i < 16; ++i) {
    const int idx = i * 256 + t;
    const int n = idx >> 6, c = idx & 63;
    const float v = tile[n][c];
    const _Float16 h = (_Float16)v;
    const _Float16 l = (_Float16)((v - (float)h) * 4096.0f);
    const size_t o = ((size_t)(tap * 512 + n0 + n)) * 1024 + c0 + c;
    WTh[o] = h;
    WTl[o] = l;
  }
}

// ---------------- Kernel 1: 3x3 conv via split-fp16 MFMA (v11) ----------------
#define AROW 40                 // 32 k-halves padded to 40
#define AS_PLANE (4 * 66 * AROW)
#define BS_PLANE (128 * AROW)
__global__ __launch_bounds__(256, 2) void conv_mfma(
    const float* __restrict__ X, const _Float16* __restrict__ WTh,
    const _Float16* __restrict__ WTl, float* __restrict__ Y)
{
  __shared__ _Float16 As[2 * AS_PLANE];   // 42,240 B
  __shared__ _Float16 Bs[2 * BS_PLANE];   // 20,480 B
  const int bid = blockIdx.x;
  const int ks = bid & 3;                 // 4 K-slices of 256 ch
  const int nt = (bid >> 2) & 3;
  const int mt = bid >> 4;
  const int t = threadIdx.x;
  const int lane = t & 63, wid = t >> 6;
  const int wm = wid >> 1, wn = wid & 1;
  const int lrow = lane & 15, quad = lane >> 4;

  floatx4 accH[4][4], accL[4][4];
  #pragma unroll
  for (int i = 0; i < 4; ++i)
    #pragma unroll
    for (int j = 0; j < 4; ++j) { accH[i][j] = (floatx4)0.f; accL[i][j] = (floatx4)0.f; }

  for (int kc = 0; kc < 8; ++kc) {
    const int c0 = ks * 256 + kc * 32;
    __syncthreads();   // prior chunk readers done
    // ---- stage A halo: 264 (yy,xx) rows x 32 ch, split to h/l, slot-swizzled ----
    for (int r = t; r < 264; r += 256) {
      const int yy = r / 66;
      const int xx = r - yy * 66;
      const int yi = mt * 2 + yy - 1;
      const int xi = xx - 1;
      const int akey = (r >> 3) & 3;
      _Float16* dsth = &As[r * AROW];
      _Float16* dstl = dsth + AS_PLANE;
      if (yi >= 0 && yi < 64 && xi >= 0 && xi < 64) {
        const float4* src = (const float4*)(X + ((size_t)(yi * 64 + xi)) * 1024 + c0);
        #pragma unroll
        for (int j = 0; j < 4; ++j) {
          const float4 va = src[2 * j], vb = src[2 * j + 1];
          const float f[8] = {va.x, va.y, va.z, va.w, vb.x, vb.y, vb.z, vb.w};
          half8 hh, hl;
          #pragma unroll
          for (int e = 0; e < 8; ++e) {
            const _Float16 h = (_Float16)f[e];
            hh[e] = h;
            hl[e] = (_Float16)((f[e] - (float)h) * 4096.0f);
          }
          const int sl = (j ^ akey) * 8;
          *(half8*)&dsth[sl] = hh;
          *(half8*)&dstl[sl] = hl;
        }
      } else {
        const half8 z = (half8)(_Float16)0.f;
        #pragma unroll
        for (int j = 0; j < 4; ++j) { *(half8*)&dsth[j * 8] = z; *(half8*)&dstl[j * 8] = z; }
      }
    }
    for (int tap = 0; tap < 9; ++tap) {
      if (tap > 0) __syncthreads();   // prior tap's B readers done
      {   // ---- stage B: 256 rows (hl,n) x 32 halves, slot-swizzled ----
        const int hl = t >> 7, n = t & 127;
        const int bkey = (n >> 3) & 3;
        const _Float16* src = (hl ? WTl : WTh) +
            ((size_t)(tap * 512 + nt * 128 + n)) * 1024 + c0;
        _Float16* dst = &Bs[hl * BS_PLANE + n * AROW];
        #pragma unroll
        for (int j = 0; j < 4; ++j)
          *(half8*)&dst[(j ^ bkey) * 8] = *(const half8*)&src[j * 8];
      }
      __syncthreads();   // A (first tap) + B visible
      const int dy = tap / 3 - 1, dx = tap - (tap / 3) * 3 - 1;
      const int yy = wm + dy + 1;
      const int xxb = dx + 1;
      half8 Ah[4], Al[4], Bh[4], Bl[4];
      #pragma unroll
      for (int fm = 0; fm < 4; ++fm) {
        const int row = yy * 66 + xxb + fm * 16 + lrow;
        const int idx = row * AROW + ((quad ^ ((row >> 3) & 3)) * 8);
        Ah[fm] = *(const half8*)&As[idx];
        Al[fm] = *(const half8*)&As[idx + AS_PLANE];
      }
      #pragma unroll
      for (int fn = 0; fn < 4; ++fn) {
        const int row = wn * 64 + fn * 16 + lrow;
        const int idx = row * AROW + ((quad ^ ((row >> 3) & 3)) * 8);
        Bh[fn] = *(const half8*)&Bs[idx];
        Bl[fn] = *(const half8*)&Bs[idx + BS_PLANE];
      }
      #pragma unroll
      for (int fm = 0; fm < 4; ++fm)
        #pragma unroll
        for (int fn = 0; fn < 4; ++fn) {
          accH[fm][fn] = __builtin_amdgcn_mfma_f32_16x16x32_f16(Ah[fm], Bh[fn], accH[fm][fn], 0, 0, 0);
          accL[fm][fn] = __builtin_amdgcn_mfma_f32_16x16x32_f16(Al[fm], Bh[fn], accL[fm][fn], 0, 0, 0);
          accL[fm][fn] = __builtin_amdgcn_mfma_f32_16x16x32_f16(Ah[fm], Bl[fn], accL[fm][fn], 0, 0, 0);
        }
    }
  }
  // ---- epilogue: combine scales, atomic-accumulate (4 K-slices per output) ----
  const int m0 = mt * 128 + wm * 64;
  const int n0 = nt * 128 + wn * 64;
  #pragma unroll
  for (int fm = 0; fm < 4; ++fm)
    #pragma unroll
    for (int fn = 0; fn < 4; ++fn) {
      const int n = n0 + fn * 16 + lrow;
      #pragma unroll
      for (int r = 0; r < 4; ++r) {
        const int m = m0 + fm * 16 + quad * 4 + r;
        atomicAdd(&Y[(size_t)m * 512 + n],
                  accH[fm][fn][r] + accL[fm][fn][r] * (1.0f / 4096.0f));
      }
    }
}

// ---------------- Kernel 2: bias+ReLU + 1x1 heads + softmax(6) + decode + ext init ----------------
__global__ __launch_bounds__(64) void heads_decode(
    const float* __restrict__ Yx, const float* __restrict__ Bc,
    const float* __restrict__ Wcls, const float* __restrict__ bcls,
    const float* __restrict__ Wreg, const float* __restrict__ breg,
    float* __restrict__ boxes, float* __restrict__ scores, int* __restrict__ ext)
{
  __shared__ float xs[512];
  const int pos = blockIdx.x;
  const int l = threadIdx.x;
  if (l == 0 && pos < NWORDS) ext[pos] = pos;
  const float* xrow = Yx + (size_t)pos * 512;
  float4 v0 = *(const float4*)&xrow[l * 8];
  float4 v1 = *(const float4*)&xrow[l * 8 + 4];
  const float4 b0 = *(const float4*)&Bc[l * 8];
  const float4 b1 = *(const float4*)&Bc[l * 8 + 4];
  xs[l * 8 + 0] = fmaxf(v0.x + b0.x, 0.f);
  xs[l * 8 + 1] = fmaxf(v0.y + b0.y, 0.f);
  xs[l * 8 + 2] = fmaxf(v0.z + b0.z, 0.f);
  xs[l * 8 + 3] = fmaxf(v0.w + b0.w, 0.f);
  xs[l * 8 + 4] = fmaxf(v1.x + b1.x, 0.f);
  xs[l * 8 + 5] = fmaxf(v1.y + b1.y, 0.f);
  xs[l * 8 + 6] = fmaxf(v1.z + b1.z, 0.f);
  xs[l * 8 + 7] = fmaxf(v1.w + b1.w, 0.f);
  __syncthreads();

  const float* wp;
  int oc;
  float bini;
  if (l < 6)       { wp = Wcls + l;       oc = 6;  bini = bcls[l]; }
  else if (l < 18) { wp = Wreg + (l - 6); oc = 12; bini = breg[l - 6]; }
  else             { wp = Wcls;           oc = 0;  bini = 0.f; }
  float acc = bini;
  const float* p = wp;
  #pragma unroll 4
  for (int c = 0; c < 512; ++c) { acc = fmaf(xs[c], *p, acc); p += oc; }

  const float l0 = __shfl(acc, 0), l1 = __shfl(acc, 1), l2 = __shfl(acc, 2);
  const float l3 = __shfl(acc, 3), l4 = __shfl(acc, 4), l5 = __shfl(acc, 5);
  const int a = (l < 3) ? l : 0;
  const float d0 = __shfl(acc, 6 + a * 4 + 0);
  const float d1 = __shfl(acc, 6 + a * 4 + 1);
  const float d2 = __shfl(acc, 6 + a * 4 + 2);
  const float d3 = __shfl(acc, 6 + a * 4 + 3);

  const float mx = fmaxf(fmaxf(fmaxf(l0, l1), fmaxf(l2, l3)), fmaxf(l4, l5));
  const float e0 = expf(l0 - mx), e1 = expf(l1 - mx), e2 = expf(l2 - mx);
  const float e3 = expf(l3 - mx), e4 = expf(l4 - mx), e5 = expf(l5 - mx);
  const float den = ((((e0 + e1) + e2) + e3) + e4) + e5;
  const float esel = (a == 0) ? e1 : ((a == 1) ? e3 : e5);
  const float sc = esel / den;

  const int px = pos & 63, py = pos >> 6;
  const float cx = (px + 0.5f) * 16.0f;
  const float cy = (py + 0.5f) * 16.0f;
  const float ratio = (a == 0) ? 0.5f : ((a == 1) ? 1.0f : 2.0f);
  const float sq = sqrtf(ratio);
  const float wsz = 128.0f * sq;
  const float hsz = 128.0f / sq;
  const float a0 = cx - wsz * 0.5f;
  const float a1 = cy - hsz * 0.5f;
  const float a2 = cx + wsz * 0.5f;
  const float a3 = cy + hsz * 0.5f;
  const float w = a2 - a0, h = a3 - a1;
  const float xc = __fadd_rn(__fmul_rn(__fadd_rn(a0, a2), 0.5f), __fmul_rn(d0, w));
  const float yc = __fadd_rn(__fmul_rn(__fadd_rn(a1, a3), 0.5f), __fmul_rn(d1, h));
  const float nw = __fmul_rn(w, expf(d2));
  const float nh = __fmul_rn(h, expf(d3));
  float4 box;
  box.x = __fsub_rn(xc, __fmul_rn(nw, 0.5f));
  box.y = __fsub_rn(yc, __fmul_rn(nh, 0.5f));
  box.z = __fadd_rn(xc, __fmul_rn(nw, 0.5f));
  box.w = __fadd_rn(yc, __fmul_rn(nh, 0.5f));

  if (l < 3) {
    const int idx = pos * 3 + a;
    *(float4*)&boxes[idx * 4] = box;
    scores[idx] = sc;
  }
}

// ---------------- Kernel 3: suppression bit-matrix (column-major) + extent ----------------
__global__ __launch_bounds__(256) void build_mask(
    const float* __restrict__ boxes, u64* __restrict__ maskT,
    int* __restrict__ ext)
{
  const int w  = blockIdx.x;
  const int ci = blockIdx.y;
  if (w < ci) return;
  __shared__ float4 rb[64];
  __shared__ int anyf;
  const int t = threadIdx.x;
  const int lane = t & 63, wid = t >> 6;
  if (t == 0) anyf = 0;
  if (t < 64) rb[t] = *(const float4*)&boxes[(ci * 64 + t) * 4];
  const float4 cb = *(const float4*)&boxes[(w * 64 + lane) * 4];
  const float careaa = __fmul_rn(cb.z - cb.x, cb.w - cb.y);
  const int jglob = w * 64 + lane;
  __syncthreads();
  bool any = false;
  for (int rr = 0; rr < 16; ++rr) {
    const int r = wid * 16 + rr;
    const int row = ci * 64 + r;
    const float4 rx = rb[r];
    const float ra = __fmul_rn(rx.z - rx.x, rx.w - rx.y);
    const float xx1 = fmaxf(rx.x, cb.x);
    const float yy1 = fmaxf(rx.y, cb.y);
    const float xx2 = fminf(rx.z, cb.z);
    const float yy2 = fminf(rx.w, cb.w);
    const float iw = fmaxf(__fsub_rn(xx2, xx1), 0.f);
    const float ih = fmaxf(__fsub_rn(yy2, yy1), 0.f);
    const float inter = __fmul_rn(iw, ih);
    const float den = __fadd_rn(__fsub_rn(__fadd_rn(ra, careaa), inter), 1e-9f);
    const float iou = __fdiv_rn(inter, den);
    const bool bit = (iou > NMS_THRESH) && (jglob > row);
    any |= bit;
    const u64 word = __ballot(bit ? 1 : 0);
    if (lane == 0) maskT[(size_t)w * NBOX + row] = word;
  }
  if (any) anyf = 1;
  __syncthreads();
  if (t == 0 && anyf && w > ci) atomicMax(&ext[ci], w);
}

// ---------------- Kernel 4: greedy NMS scan (v12 = v10 + ping-pong, no rotation) ----
// v10's step still paid an exposed memory latency: mA[j]=mB[j] rotation forced
// vmcnt(0) on the current step's prefetch before its barrier. v12 unrolls by 2 with
// NAMED ping-pong register sets (mA0..7 / mB0..7): step even consumes A & prefetches
// B, step odd consumes B & prefetches A. Loads get a full step + barrier to land.
// Stale-guard invariant: prefetch guard (c+2+wsub <= extS[c+1]) == consume guard.
__device__ __forceinline__ u64 rl64(unsigned lo, unsigned hi, int l) {
  const unsigned a = (unsigned)__builtin_amdgcn_readlane((int)lo, l);
  const unsigned b = (unsigned)__builtin_amdgcn_readlane((int)hi, l);
  return ((u64)b << 32) | (u64)a;
}

#define NSTEP(C_, MU, DU, MP, DP)                                               \
  do {                                                                          \
    const int c_ = (C_);                                                        \
    const int e_ = extS[c_];                                                    \
    const u64 aw0v_ = alive[c_];                                                \
    /* ---- prefetch for c_+1 into the P set (consumed next step) ---- */       \
    if (c_ + 1 < NWORDS) {                                                      \
      DP = maskT[(size_t)(c_ + 1) * NBOX + (size_t)(c_ + 1) * 64 + lane];       \
      const int en_ = extS[c_ + 1];                                             \
      const int t0n_ = c_ + 2 + wsub;                                           \
      if (t0n_ <= en_) {                                                        \
        const u64* cbp_ = maskT + (size_t)t0n_ * NBOX + (size_t)(c_ + 1) * 64 + sub * 8; \
        MP##0 = cbp_[0]; MP##1 = cbp_[1]; MP##2 = cbp_[2]; MP##3 = cbp_[3];     \
        MP##4 = cbp_[4]; MP##5 = cbp_[5]; MP##6 = cbp_[6]; MP##7 = cbp_[7];     \
      }                                                                         \
    }                                                                           \
    /* ---- phase A: S-ballot fast path + scalar greedy (replicated/wave) ---- */ \
    const unsigned awlo_ = (unsigned)__builtin_amdgcn_readfirstlane((int)(unsigned)(aw0v_ & 0xffffffffull)); \
    const unsigned awhi_ = (unsigned)__builtin_amdgcn_readfirstlane((int)(unsigned)(aw0v_ >> 32)); \
    const u64 aw0_ = ((u64)awhi_ << 32) | (u64)awlo_;                           \
    if (aw0_) {                                                                 \
      const unsigned dlo_ = (unsigned)(DU & 0xffffffffull);                     \
      const unsigned dhi_ = (unsigned)(DU >> 32);                               \
      u64 aw_ = aw0_;                                                           \
      const bool sb_ = ((aw0_ >> lane) & 1ull) && ((DU & aw0_) != 0ull);        \
      u64 pending_ = __ballot(sb_ ? 1 : 0);                                     \
      while (pending_) {                                                        \
        const u64 p0_ = pending_;                                               \
        const u64 p1_ = p0_ & (p0_ - 1);                                        \
        const u64 p2_ = p1_ & (p1_ - 1);                                        \
        const u64 p3_ = p2_ & (p2_ - 1);                                        \
        const int b0_ = __builtin_ctzll(p0_);                                   \
        const int b1_ = p1_ ? __builtin_ctzll(p1_) : 64;                        \
        const int b2_ = p2_ ? __builtin_ctzll(p2_) : 64;                        \
        const int b3_ = p3_ ? __builtin_ctzll(p3_) : 64;                        \
        const u64 r0_ = rl64(dlo_, dhi_, b0_);                                  \
        const u64 r1_ = rl64(dlo_, dhi_, b1_ & 63);                             \
        const u64 r2_ = rl64(dlo_, dhi_, b2_ & 63);                             \
        const u64 r3_ = rl64(dlo_, dhi_, b3_ & 63);                             \
        u64 supp_ = r0_;                                                        \
        u64 done_ = 1ull << b0_;                                                \
        const u64 k1_ = ((b1_ < 64) & !((supp_ >> (b1_ & 63)) & 1ull)) ? ~0ull : 0ull; \
        supp_ |= r1_ & k1_;  done_ |= (1ull << (b1_ & 63)) & k1_;               \
        const u64 k2_ = ((b2_ < 64) & !((supp_ >> (b2_ & 63)) & 1ull)) ? ~0ull : 0ull; \
        supp_ |= r2_ & k2_;  done_ |= (1ull << (b2_ & 63)) & k2_;               \
        const u64 k3_ = ((b3_ < 64) & !((supp_ >> (b3_ & 63)) & 1ull)) ? ~0ull : 0ull; \
        supp_ |= r3_ & k3_;  done_ |= (1ull << (b3_ & 63)) & k3_;               \
        aw_ &= ~supp_;                                                          \
        pending_ &= ~(supp_ | done_);                                           \
      }                                                                         \
      /* ---- phase B: per-lane select from prefetched columns + LDS atomicAnd ---- */ \
      const int t0_ = c_ + 1 + wsub;                                            \
      if (t0_ <= e_) {                                                          \
        const unsigned oct_ = (unsigned)(aw_ >> (sub * 8)) & 0xffu;             \
        u64 sup_ = 0ull;                                                        \
        if (oct_ & 1u)   sup_ |= MU##0;                                         \
        if (oct_ & 2u)   sup_ |= MU##1;                                         \
        if (oct_ & 4u)   sup_ |= MU##2;                                         \
        if (oct_ & 8u)   sup_ |= MU##3;                                         \
        if (oct_ & 16u)  sup_ |= MU##4;                                         \
        if (oct_ & 32u)  sup_ |= MU##5;                                         \
        if (oct_ & 64u)  sup_ |= MU##6;                                         \
        if (oct_ & 128u) sup_ |= MU##7;                                         \
        if (sup_) atomicAnd((unsigned long long*)&alive[t0_], ~sup_);           \
      }                                                                         \
      /* rare overflow passes when the extent spans more than 32 words */       \
      for (int base_ = c_ + 33; base_ <= e_; base_ += 32) {                     \
        const int tw_ = base_ + wsub;                                           \
        if (tw_ <= e_) {                                                        \
          const u64* cbp_ = maskT + (size_t)tw_ * NBOX + (size_t)c_ * 64 + sub * 8; \
          u64 m_[8];                                                            \
          _Pragma("unroll")                                                     \
          for (int j_ = 0; j_ < 8; ++j_) m_[j_] = cbp_[j_];                     \
          const unsigned oct_ = (unsigned)(aw_ >> (sub * 8)) & 0xffu;           \
          u64 sup_ = 0ull;                                                      \
          _Pragma("unroll")                                                     \
          for (int j_ = 0; j_ < 8; ++j_) if ((oct_ >> j_) & 1u) sup_ |= m_[j_]; \
          if (sup_) atomicAnd((unsigned long long*)&alive[tw_], ~sup_);         \
        }                                                                       \
      }                                                                         \
      if (t == 0) alive[c_] = aw_;                                              \
    }                                                                           \
    /* raw barrier: drain LDS ops only; global prefetches stay in flight */     \
    asm volatile("s_waitcnt lgkmcnt(0)" ::: "memory");                          \
    __builtin_amdgcn_s_barrier();                                               \
    asm volatile("" ::: "memory");                                              \
  } while (0)

__global__ __launch_bounds__(256) void nms_scan(
    const float* __restrict__ scores, const u64* __restrict__ maskT,
    const int* __restrict__ ext, u64* __restrict__ aliveOut)
{
  __shared__ u64 alive[NWORDS];
  __shared__ int extS[NWORDS];
  const int t = threadIdx.x;
  const int lane = t & 63;
  const int wsub = t >> 3;   // 0..31: which downstream word this thread serves
  const int sub = t & 7;     // which 8-row octet of that word's column
  if (t < NWORDS) {
    u64 wbits = 0ull;
    const float4* sp = (const float4*)(scores + t * 64);
    #pragma unroll
    for (int q = 0; q < 16; ++q) {
      const float4 s = sp[q];
      if (s.x > POS_THRESH) wbits |= (1ull << (q * 4 + 0));
      if (s.y > POS_THRESH) wbits |= (1ull << (q * 4 + 1));
      if (s.z > POS_THRESH) wbits |= (1ull << (q * 4 + 2));
      if (s.w > POS_THRESH) wbits |= (1ull << (q * 4 + 3));
    }
    alive[t] = wbits;
    extS[t] = ext[t];
  }
  // ping-pong register sets (named scalars -> stay in VGPRs)
  u64 mA0 = 0, mA1 = 0, mA2 = 0, mA3 = 0, mA4 = 0, mA5 = 0, mA6 = 0, mA7 = 0;
  u64 mB0 = 0, mB1 = 0, mB2 = 0, mB3 = 0, mB4 = 0, mB5 = 0, mB6 = 0, mB7 = 0;
  u64 dgA = 0, dgB = 0;
  // prologue: preload set A for c = 0 (stays in flight across the init barrier)
  const int e0 = ext[0];
  if (1 + wsub <= e0) {
    const u64* cbp = maskT + (size_t)(1 + wsub) * NBOX + sub * 8;
    mA0 = cbp[0]; mA1 = cbp[1]; mA2 = cbp[2]; mA3 = cbp[3];
    mA4 = cbp[4]; mA5 = cbp[5]; mA6 = cbp[6]; mA7 = cbp[7];
  }
  dgA = maskT[lane];   // diagonal block (0,0), row = lane
  asm volatile("s_waitcnt lgkmcnt(0)" ::: "memory");
  __builtin_amdgcn_s_barrier();
  asm volatile("" ::: "memory");

  for (int c = 0; c < NWORDS; c += 2) {
    NSTEP(c,     mA, dgA, mB, dgB);
    NSTEP(c + 1, mB, dgB, mA, dgA);
  }
  if (t < NWORDS) aliveOut[t] = alive[t];
}

// ---------------- Kernel 5: masked output ----------------
__global__ __launch_bounds__(256) void write_output(
    const float* __restrict__ boxes, const u64* __restrict__ alive,
    float* __restrict__ out)
{
  const int i = blockIdx.x * 256 + threadIdx.x;
  if (i < NBOX) {
    const bool k = (alive[i >> 6] >> (i & 63)) & 1ull;
    const float4 b = *(const float4*)&boxes[i * 4];
    const float4 z = {0.f, 0.f, 0.f, 0.f};
    *(float4*)&out[i * 4] = k ? b : z;
  }
}

extern "C" void kernel_launch(void* const* d_in, const int* in_sizes, int n_in,
                              void* d_out, int out_size, void* d_ws, size_t ws_size,
                              hipStream_t stream) {
  const float* X    = (const float*)d_in[0];  // (1,64,64,1024)
  const float* Wc   = (const float*)d_in[1];  // (3,3,1024,512)
  const float* Bc   = (const float*)d_in[2];  // (512,)
  const float* Wcls = (const float*)d_in[3];  // (1,1,512,6)
  const float* bcls = (const float*)d_in[4];  // (6,)
  const float* Wreg = (const float*)d_in[5];  // (1,1,512,12)
  const float* breg = (const float*)d_in[6];  // (12,)

  char* ws = (char*)d_ws;
  float*     Y      = (float*)    (ws);                 // 8,388,608 B (raw conv sums)
  float*     boxes  = (float*)    (ws + 8388608);       //   196,608 B
  float*     scores = (float*)    (ws + 8585216);       //    49,152 B
  u64*       aliveG = (u64*)      (ws + 8634368);       //     1,536 B
  int*       extG   = (int*)      (ws + 8635904);       //       768 B
  // conv phase uses [8,636,672 .. 27,511,040) for WTh+WTl; maskT reuses the
  // SAME region after conv is done (both exactly 18,874,368 B).
  _Float16*  WTh    = (_Float16*) (ws + 8636672);       // 9,437,184 B
  _Float16*  WTl    = (_Float16*) (ws + 18073856);      // 9,437,184 B
  u64*       maskT  = (u64*)      (ws + 8636672);       // 18,874,368 B (post-conv)

  zero_y      <<<2048, 256, 0, stream>>>((float4*)Y);
  prep_wt     <<<1152, 256, 0, stream>>>(Wc, WTh, WTl);
  conv_mfma   <<<512, 256, 0, stream>>>(X, WTh, WTl, Y);
  heads_decode<<<4096, 64, 0, stream>>>(Y, Bc, Wcls, bcls, Wreg, breg, boxes, scores, extG);
  build_mask  <<<dim3(192, 192), 256, 0, stream>>>(boxes, maskT, extG);
  nms_scan    <<<1, 256, 0, stream>>>(scores, maskT, extG, aliveG);
  write_output<<<48, 256, 0, stream>>>(boxes, aliveG, (float*)d_out);
}